// Round 1
// baseline (2170.858 us; speedup 1.0000x reference)
//
#include <hip/hip_runtime.h>
#include <hip/hip_bf16.h>

// ---------------- problem constants ----------------
#define NP     200000   // players
#define NPOS   320
#define NT     32
#define FEAT   128
#define EMB    64
#define HID    128
#define EP2P   400000
#define EP2T   640
#define ECHEM  1000000

#define CHEM_CAP 32     // max in-degree per player (Poisson(5); P(>=32)*NP ~ 1e-10)
#define P2P_CAP  2048   // max in-degree per position (mean 1250, sigma ~35)

// ---------------- generic tall-skinny linear: out = act(A @ W + b) ----------------
// thread-per-row; W accessed with wave-uniform addresses (scalar loads), j chunked
// by 32 to keep SGPR/VGPR pressure low.
template<int K, int M, bool RELU>
__global__ __launch_bounds__(256) void linear_rows(const float* __restrict__ A,
                                                   const float* __restrict__ W,
                                                   const float* __restrict__ bias,
                                                   float* __restrict__ out, int N)
{
    int r = blockIdx.x * 256 + threadIdx.x;
    if (r >= N) return;
    const float* a = A + (size_t)r * K;
    float* o = out + (size_t)r * M;
#pragma unroll 1
    for (int j0 = 0; j0 < M; j0 += 32) {
        float acc[32];
#pragma unroll
        for (int j = 0; j < 32; ++j) acc[j] = bias[j0 + j];
#pragma unroll 4
        for (int k = 0; k < K; ++k) {
            float ak = a[k];
            const float* wr = W + (size_t)k * M + j0;
#pragma unroll
            for (int j = 0; j < 32; ++j) acc[j] += ak * wr[j];
        }
#pragma unroll
        for (int j = 0; j < 32; ++j) {
            float v = acc[j];
            if (RELU) v = fmaxf(v, 0.f);
            o[j0 + j] = v;
        }
    }
}

// ---------------- init: zero counters/slots, gather initial position embeds ----------------
__global__ __launch_bounds__(256) void init_kernel(int* __restrict__ chem_cnt,
                                                   int* __restrict__ p2p_cnt,
                                                   unsigned* __restrict__ maxkey,
                                                   float* __restrict__ Zp,
                                                   const int* __restrict__ pos_idx,
                                                   const float* __restrict__ pos_table,
                                                   float* __restrict__ pos0)
{
    int t = blockIdx.x * 256 + threadIdx.x;
    if (t < NP) chem_cnt[t] = 0;
    if (t < NPOS) p2p_cnt[t] = 0;
    if (t < NPOS * EMB) pos0[t] = pos_table[pos_idx[t >> 6] * EMB + (t & 63)];
    if (t == 0) { *maxkey = 0u; *Zp = 0.f; }
}

// ---------------- chem attention: scores + global max ----------------
__global__ __launch_bounds__(256) void chem_scores(const float* __restrict__ Qp,
                                                   const float* __restrict__ Kp,
                                                   const int* __restrict__ chem, // 2 x ECHEM
                                                   float* __restrict__ sc,
                                                   unsigned* __restrict__ maxkey)
{
    __shared__ float wmax[4];
    int tid = threadIdx.x;
    int e = blockIdx.x * 16 + (tid >> 4);   // 16 lanes per edge, grid exact
    int sub = tid & 15;
    int src = chem[e], dst = chem[ECHEM + e];
    const float4* q = (const float4*)(Qp + (size_t)dst * EMB);
    const float4* k = (const float4*)(Kp + (size_t)src * EMB);
    float4 qv = q[sub], kv = k[sub];
    float p = qv.x * kv.x + qv.y * kv.y + qv.z * kv.z + qv.w * kv.w;
    p += __shfl_xor(p, 1); p += __shfl_xor(p, 2);
    p += __shfl_xor(p, 4); p += __shfl_xor(p, 8);
    float s = p * 0.125f;                    // / sqrt(64)
    if (sub == 0) sc[e] = s;
    // block max -> one atomicMax per block (monotone uint key)
    float m = s;
    for (int off = 16; off < 64; off <<= 1) m = fmaxf(m, __shfl_xor(m, off));
    if ((tid & 63) == 0) wmax[tid >> 6] = m;
    __syncthreads();
    if (tid == 0) {
        float mm = fmaxf(fmaxf(wmax[0], wmax[1]), fmaxf(wmax[2], wmax[3]));
        unsigned b = __float_as_uint(mm);
        unsigned key = (b & 0x80000000u) ? ~b : (b | 0x80000000u);
        atomicMax(maxkey, key);
    }
}

// ---------------- exp(s - m), accumulate Z ----------------
__global__ __launch_bounds__(256) void chem_expsum(float* __restrict__ sc,
                                                   const unsigned* __restrict__ maxkey,
                                                   float* __restrict__ Zp)
{
    __shared__ float wsum[4];
    unsigned key = *maxkey;
    unsigned b = (key & 0x80000000u) ? (key ^ 0x80000000u) : ~key;
    float m = __uint_as_float(b);
    int e = blockIdx.x * 256 + threadIdx.x;
    float w = 0.f;
    if (e < ECHEM) { w = __expf(sc[e] - m); sc[e] = w; }
    float ssum = w;
    for (int off = 1; off < 64; off <<= 1) ssum += __shfl_xor(ssum, off);
    if ((threadIdx.x & 63) == 0) wsum[threadIdx.x >> 6] = ssum;
    __syncthreads();
    if (threadIdx.x == 0) atomicAdd(Zp, wsum[0] + wsum[1] + wsum[2] + wsum[3]);
}

// ---------------- bucket edges by dst (capacity-bounded lists) ----------------
__global__ __launch_bounds__(256) void chem_scatter(const int* __restrict__ chem,
                                                    int* __restrict__ cnt,
                                                    int* __restrict__ list)
{
    int e = blockIdx.x * 256 + threadIdx.x;
    if (e >= ECHEM) return;
    int d = chem[ECHEM + e];
    int pos = atomicAdd(&cnt[d], 1);
    if (pos < CHEM_CAP) list[d * CHEM_CAP + pos] = e;
}

__global__ __launch_bounds__(256) void p2p_scatter(const int* __restrict__ p2p,
                                                   int* __restrict__ cnt,
                                                   int* __restrict__ list)
{
    int e = blockIdx.x * 256 + threadIdx.x;
    if (e >= EP2P) return;
    int s = p2p[e], d = p2p[EP2P + e];
    int pos = atomicAdd(&cnt[d], 1);
    if (pos < P2P_CAP) list[d * P2P_CAP + pos] = s;   // store src directly
}

// ---------------- chem segment aggregation: emb2 = emb + sum attn*Vp ----------------
// one wave per dst; prefetch edge list across lanes, broadcast via shfl.
__global__ __launch_bounds__(256) void chem_agg(const float* __restrict__ emb,
                                                const float* __restrict__ Vp,
                                                const float* __restrict__ wexp,
                                                const int* __restrict__ chem_src,
                                                const int* __restrict__ cnt,
                                                const int* __restrict__ list,
                                                const float* __restrict__ Zp,
                                                float* __restrict__ emb2)
{
    int wave = threadIdx.x >> 6, lane = threadIdx.x & 63;
    int d = blockIdx.x * 4 + wave;
    if (d >= NP) return;
    float invZ = 1.f / Zp[0];
    int c = cnt[d]; if (c > CHEM_CAP) c = CHEM_CAP;
    int sv = 0; float wv = 0.f;
    if (lane < c) {
        int e = list[d * CHEM_CAP + lane];
        sv = chem_src[e];
        wv = wexp[e] * invZ;
    }
    float acc = 0.f;
    for (int i = 0; i < c; ++i) {
        int s = __shfl(sv, i);
        float w = __shfl(wv, i);
        acc += w * Vp[(size_t)s * EMB + lane];
    }
    emb2[(size_t)d * EMB + lane] = emb[(size_t)d * EMB + lane] + acc;
}

// ---------------- p2p segment aggregation (mean of Mp over in-edges) ----------------
__global__ __launch_bounds__(256) void p2p_agg(const float* __restrict__ Mp,
                                               const int* __restrict__ cnt,
                                               const int* __restrict__ list,
                                               float* __restrict__ pos_agg)
{
    __shared__ float part[4 * 64];
    int d = blockIdx.x;                         // 320 blocks
    int wave = threadIdx.x >> 6, lane = threadIdx.x & 63;
    int c = cnt[d];
    int cl = c > P2P_CAP ? P2P_CAP : c;
    float acc = 0.f;
    for (int i0 = wave * 64; i0 < cl; i0 += 256) {
        int n = cl - i0; if (n > 64) n = 64;
        int sv = (lane < n) ? list[d * P2P_CAP + i0 + lane] : 0;
        for (int i = 0; i < n; ++i) {
            int s = __shfl(sv, i);
            acc += Mp[(size_t)s * EMB + lane];
        }
    }
    part[wave * 64 + lane] = acc;
    __syncthreads();
    if (wave == 0) {
        float t = part[lane] + part[64 + lane] + part[128 + lane] + part[192 + lane];
        float cn = (float)c; if (cn < 1.f) cn = 1.f;
        pos_agg[d * 64 + lane] = t / cn;
    }
}

// ---------------- position update round: pos_out = relu([pos_in, agg] @ W + b) ----------------
__global__ __launch_bounds__(256) void pos_update(const float* __restrict__ pos_in,
                                                  const float* __restrict__ agg,
                                                  const float* __restrict__ W,  // 128x64
                                                  const float* __restrict__ bias,
                                                  float* __restrict__ pos_out)
{
    int idx = blockIdx.x * 256 + threadIdx.x;   // NPOS*64 = 20480
    if (idx >= NPOS * EMB) return;
    int r = idx >> 6, j = idx & 63;
    float acc = bias[j];
    const float* pr = pos_in + r * 64;
    const float* ar = agg + r * 64;
#pragma unroll 8
    for (int k = 0; k < 64; ++k) acc += pr[k] * W[k * 64 + j];
#pragma unroll 8
    for (int k = 0; k < 64; ++k) acc += ar[k] * W[(64 + k) * 64 + j];
    pos_out[idx] = fmaxf(acc, 0.f);
}

// ---------------- p2t phase + game head, single block ----------------
__global__ __launch_bounds__(256) void p2t_and_head(
    const float* __restrict__ pos,            // 320x64 final
    const int* __restrict__ p2t_edges,        // 2x640: row0 src(pos), row1 dst(team)
    const float* __restrict__ msg_w, const float* __restrict__ msg_b,
    const float* __restrict__ upd_w, const float* __restrict__ upd_b,
    const int* __restrict__ team_indices,
    const float* __restrict__ team_table,     // 32x64
    const int* __restrict__ home_p, const int* __restrict__ away_p,
    const float* __restrict__ gp_w1, const float* __restrict__ gp_b1,
    const float* __restrict__ gp_w2, const float* __restrict__ gp_b2,
    const float* __restrict__ gp_w3, const float* __restrict__ gp_b3,
    float* __restrict__ Mt,                   // ws scratch 320x64
    float* __restrict__ out)
{
    __shared__ float tacc[NT * 64];
    __shared__ float aggbar[NT * 64];
    __shared__ float teamA[NT * 64];
    __shared__ float teamB[NT * 64];
    __shared__ int   tcnt[NT];
    __shared__ float z1[128];
    __shared__ float z2[64];
    int tid = threadIdx.x;

    // Mt = relu(pos @ msg_w + msg_b)  (320x64)
    for (int idx = tid; idx < NPOS * 64; idx += 256) {
        int r = idx >> 6, j = idx & 63;
        float acc = msg_b[j];
        for (int k = 0; k < 64; ++k) acc += pos[r * 64 + k] * msg_w[k * 64 + j];
        Mt[idx] = fmaxf(acc, 0.f);
    }
    for (int i = tid; i < NT * 64; i += 256) tacc[i] = 0.f;
    if (tid < NT) tcnt[tid] = 0;
    __threadfence_block();
    __syncthreads();

    // aggregate over 640 edges into 32 teams (LDS atomics)
    for (int e = tid; e < EP2T; e += 256) {
        int s = p2t_edges[e], d = p2t_edges[EP2T + e];
        atomicAdd(&tcnt[d], 1);
        for (int c = 0; c < 64; ++c) atomicAdd(&tacc[d * 64 + c], Mt[s * 64 + c]);
    }
    __syncthreads();
    for (int i = tid; i < NT * 64; i += 256) {
        int d = i >> 6;
        float cn = (float)tcnt[d]; if (cn < 1.f) cn = 1.f;
        aggbar[i] = tacc[i] / cn;
        teamA[i] = team_table[team_indices[d] * 64 + (i & 63)];
    }
    __syncthreads();

    // 3 rounds of team update (agg constant across rounds)
    float* tin = teamA; float* tout = teamB;
    for (int round = 0; round < 3; ++round) {
        for (int i = tid; i < NT * 64; i += 256) {
            int r = i >> 6, j = i & 63;
            float acc = upd_b[j];
            for (int k = 0; k < 64; ++k) acc += tin[r * 64 + k] * upd_w[k * 64 + j];
            for (int k = 0; k < 64; ++k) acc += aggbar[r * 64 + k] * upd_w[(64 + k) * 64 + j];
            tout[i] = fmaxf(acc, 0.f);
        }
        __syncthreads();
        float* tmp = tin; tin = tout; tout = tmp;
    }

    // game predictor
    int home = home_p[0], away = away_p[0];
    if (tid < 128) {
        float acc = gp_b1[tid];
        for (int k = 0; k < 128; ++k) {
            float g = (k < 64) ? tin[home * 64 + k] : tin[away * 64 + (k - 64)];
            acc += g * gp_w1[k * 128 + tid];
        }
        z1[tid] = fmaxf(acc, 0.f);
    }
    __syncthreads();
    if (tid < 64) {
        float acc = gp_b2[tid];
        for (int k = 0; k < 128; ++k) acc += z1[k] * gp_w2[k * 64 + tid];
        z2[tid] = fmaxf(acc, 0.f);
    }
    __syncthreads();
    if (tid == 0) {
        float acc = gp_b3[0];
        for (int k = 0; k < 64; ++k) acc += z2[k] * gp_w3[k];
        out[0] = 1.f / (1.f + __expf(-acc));
    }
}

// ---------------- host launcher ----------------
extern "C" void kernel_launch(void* const* d_in, const int* in_sizes, int n_in,
                              void* d_out, int out_size, void* d_ws, size_t ws_size,
                              hipStream_t stream)
{
    const float* X        = (const float*)d_in[0];
    const int*   pos_idx  = (const int*)d_in[1];
    const int*   team_idx = (const int*)d_in[2];
    const int*   p2p      = (const int*)d_in[3];
    const int*   p2t      = (const int*)d_in[4];
    const int*   chem     = (const int*)d_in[5];
    const int*   home_p   = (const int*)d_in[6];
    const int*   away_p   = (const int*)d_in[7];
    const float* enc_w1   = (const float*)d_in[8];
    const float* enc_b1   = (const float*)d_in[9];
    const float* enc_w2   = (const float*)d_in[10];
    const float* enc_b2   = (const float*)d_in[11];
    const float* pos_tab  = (const float*)d_in[12];
    const float* team_tab = (const float*)d_in[13];
    const float* q_w = (const float*)d_in[14]; const float* q_b = (const float*)d_in[15];
    const float* k_w = (const float*)d_in[16]; const float* k_b = (const float*)d_in[17];
    const float* v_w = (const float*)d_in[18]; const float* v_b = (const float*)d_in[19];
    const float* p2p_msg_w = (const float*)d_in[20]; const float* p2p_msg_b = (const float*)d_in[21];
    const float* p2p_upd_w = (const float*)d_in[22]; const float* p2p_upd_b = (const float*)d_in[23];
    const float* p2t_msg_w = (const float*)d_in[24]; const float* p2t_msg_b = (const float*)d_in[25];
    const float* p2t_upd_w = (const float*)d_in[26]; const float* p2t_upd_b = (const float*)d_in[27];
    const float* gp_w1 = (const float*)d_in[28]; const float* gp_b1 = (const float*)d_in[29];
    const float* gp_w2 = (const float*)d_in[30]; const float* gp_b2 = (const float*)d_in[31];
    const float* gp_w3 = (const float*)d_in[32]; const float* gp_b3 = (const float*)d_in[33];
    float* out = (float*)d_out;

    // ---- workspace layout (bytes). peak ~312.4 MB ----
    char* ws = (char*)d_ws;
    // region [0, 102.4M): h during encoder; chem_list + p2p_list after h is dead
    float*    h         = (float*)(ws + 0);                       // NP*128 f32
    int*      chem_list = (int*)  (ws + 0);                       // NP*CHEM_CAP = 25.6MB
    int*      p2p_list  = (int*)  (ws + 25600000);                // NPOS*P2P_CAP = 2.62MB
    float*    emb       = (float*)(ws + 102400000);               // NP*64
    float*    Qp        = (float*)(ws + 153600000);               // NP*64 ; reused as emb2
    float*    emb2      = (float*)(ws + 153600000);
    float*    Kp        = (float*)(ws + 204800000);               // NP*64 ; reused as Mp
    float*    Mp        = (float*)(ws + 204800000);
    float*    Vp        = (float*)(ws + 256000000);               // NP*64
    float*    wexp      = (float*)(ws + 307200000);               // ECHEM f32
    int*      chem_cnt  = (int*)  (ws + 311200000);               // NP ints
    int*      p2p_cnt   = (int*)  (ws + 312000000);               // NPOS ints
    float*    pos_agg   = (float*)(ws + 312001280);               // 320*64
    float*    posA      = (float*)(ws + 312083200);
    float*    posB      = (float*)(ws + 312165120);
    float*    Mt        = (float*)(ws + 312247040);
    unsigned* maxkey    = (unsigned*)(ws + 312328960);
    float*    Zp        = (float*)(ws + 312328964);

    const int NB_NP = (NP + 255) / 256;       // 782

    // 0) init counters/slots + gather initial position embeds
    hipLaunchKernelGGL(init_kernel, dim3(NB_NP), dim3(256), 0, stream,
                       chem_cnt, p2p_cnt, maxkey, Zp, pos_idx, pos_tab, posA);
    // 1) encoder
    hipLaunchKernelGGL((linear_rows<128,128,true>),  dim3(NB_NP), dim3(256), 0, stream, X, enc_w1, enc_b1, h, NP);
    hipLaunchKernelGGL((linear_rows<128,64,false>),  dim3(NB_NP), dim3(256), 0, stream, h, enc_w2, enc_b2, emb, NP);
    // 2) per-player Q/K/V
    hipLaunchKernelGGL((linear_rows<64,64,false>),   dim3(NB_NP), dim3(256), 0, stream, emb, q_w, q_b, Qp, NP);
    hipLaunchKernelGGL((linear_rows<64,64,false>),   dim3(NB_NP), dim3(256), 0, stream, emb, k_w, k_b, Kp, NP);
    hipLaunchKernelGGL((linear_rows<64,64,false>),   dim3(NB_NP), dim3(256), 0, stream, emb, v_w, v_b, Vp, NP);
    // 3) edge scores + global softmax
    hipLaunchKernelGGL(chem_scores, dim3(ECHEM / 16), dim3(256), 0, stream, Qp, Kp, chem, wexp, maxkey);
    hipLaunchKernelGGL(chem_expsum, dim3((ECHEM + 255) / 256), dim3(256), 0, stream, wexp, maxkey, Zp);
    // 4) bucket chem edges by dst (h is dead now; Qp/Kp die after chem_scores)
    hipLaunchKernelGGL(chem_scatter, dim3((ECHEM + 255) / 256), dim3(256), 0, stream, chem, chem_cnt, chem_list);
    hipLaunchKernelGGL(chem_agg, dim3((NP + 3) / 4), dim3(256), 0, stream,
                       emb, Vp, wexp, chem, chem_cnt, chem_list, Zp, emb2);
    // 5) p2p: per-player messages (constant across rounds), segment-mean into positions
    hipLaunchKernelGGL((linear_rows<64,64,true>), dim3(NB_NP), dim3(256), 0, stream,
                       emb2, p2p_msg_w, p2p_msg_b, Mp, NP);
    hipLaunchKernelGGL(p2p_scatter, dim3((EP2P + 255) / 256), dim3(256), 0, stream, p2p, p2p_cnt, p2p_list);
    hipLaunchKernelGGL(p2p_agg, dim3(NPOS), dim3(256), 0, stream, Mp, p2p_cnt, p2p_list, pos_agg);
    // 6) 3 position-update rounds (tiny)
    hipLaunchKernelGGL(pos_update, dim3((NPOS * EMB + 255) / 256), dim3(256), 0, stream,
                       posA, pos_agg, p2p_upd_w, p2p_upd_b, posB);
    hipLaunchKernelGGL(pos_update, dim3((NPOS * EMB + 255) / 256), dim3(256), 0, stream,
                       posB, pos_agg, p2p_upd_w, p2p_upd_b, posA);
    hipLaunchKernelGGL(pos_update, dim3((NPOS * EMB + 255) / 256), dim3(256), 0, stream,
                       posA, pos_agg, p2p_upd_w, p2p_upd_b, posB);
    // 7) p2t phase + game head (single block)
    hipLaunchKernelGGL(p2t_and_head, dim3(1), dim3(256), 0, stream,
                       posB, p2t, p2t_msg_w, p2t_msg_b, p2t_upd_w, p2t_upd_b,
                       team_idx, team_tab, home_p, away_p,
                       gp_w1, gp_b1, gp_w2, gp_b2, gp_w3, gp_b3, Mt, out);
}

// Round 2
// 1641.853 us; speedup vs baseline: 1.3222x; 1.3222x over previous
//
#include <hip/hip_runtime.h>
#include <hip/hip_bf16.h>

// ---------------- problem constants ----------------
#define NP     200000   // players
#define NPOS   320
#define NT     32
#define FEAT   128
#define EMB    64
#define HID    128
#define EP2P   400000
#define EP2T   640
#define ECHEM  1000000

#define CHEM_CAP 32     // max in-degree per player (Poisson(5); P(>=32)*NP ~ 1e-10)
#define P2P_CAP  2048   // max in-degree per position (mean 1250, sigma ~35)
#define T2_CAP   64     // max in-degree per team (mean 20, sigma 4.4)

#define SC_GRID  2048   // persistent blocks for edge passes -> 2048 single-address atomics, not 62500

// ---------------- generic tall-skinny linear: out = act(A @ W + b) ----------------
// thread-per-row; W accessed with wave-uniform addresses (scalar loads), A as float4.
template<int K, int M, bool RELU>
__global__ __launch_bounds__(256) void linear_rows(const float* __restrict__ A,
                                                   const float* __restrict__ W,
                                                   const float* __restrict__ bias,
                                                   float* __restrict__ out, int N)
{
    int r = blockIdx.x * 256 + threadIdx.x;
    if (r >= N) return;
    const float4* a4 = (const float4*)(A + (size_t)r * K);
    float* o = out + (size_t)r * M;
#pragma unroll 1
    for (int j0 = 0; j0 < M; j0 += 32) {
        float acc[32];
#pragma unroll
        for (int j = 0; j < 32; ++j) acc[j] = bias[j0 + j];
#pragma unroll 2
        for (int k4 = 0; k4 < K / 4; ++k4) {
            float4 av = a4[k4];
            const float* w0 = W + (size_t)(4 * k4) * M + j0;
#pragma unroll
            for (int j = 0; j < 32; ++j) acc[j] += av.x * w0[j];
            const float* w1 = w0 + M;
#pragma unroll
            for (int j = 0; j < 32; ++j) acc[j] += av.y * w1[j];
            const float* w2 = w1 + M;
#pragma unroll
            for (int j = 0; j < 32; ++j) acc[j] += av.z * w2[j];
            const float* w3 = w2 + M;
#pragma unroll
            for (int j = 0; j < 32; ++j) acc[j] += av.w * w3[j];
        }
#pragma unroll
        for (int j = 0; j < 32; ++j) {
            float v = acc[j];
            if (RELU) v = fmaxf(v, 0.f);
            o[j0 + j] = v;
        }
    }
}

// ---------------- fused Q/K/V: emb row held in registers, 3 weight passes ----------------
__global__ __launch_bounds__(256) void qkv_rows(const float* __restrict__ emb,
    const float* __restrict__ qw, const float* __restrict__ qb,
    const float* __restrict__ kw, const float* __restrict__ kb,
    const float* __restrict__ vw, const float* __restrict__ vb,
    float* __restrict__ Q, float* __restrict__ K, float* __restrict__ V, int N)
{
    int r = blockIdx.x * 256 + threadIdx.x;
    if (r >= N) return;
    float a[64];
    const float4* a4 = (const float4*)(emb + (size_t)r * 64);
#pragma unroll
    for (int i = 0; i < 16; ++i) {
        float4 t = a4[i];
        a[4*i] = t.x; a[4*i+1] = t.y; a[4*i+2] = t.z; a[4*i+3] = t.w;
    }
    const float* Wm[3] = {qw, kw, vw};
    const float* Bm[3] = {qb, kb, vb};
    float*       Om[3] = {Q, K, V};
#pragma unroll 1
    for (int m = 0; m < 3; ++m) {
        const float* W = Wm[m];
        const float* bvec = Bm[m];
        float* O = Om[m] + (size_t)r * 64;
#pragma unroll 1
        for (int j0 = 0; j0 < 64; j0 += 32) {
            float acc[32];
#pragma unroll
            for (int j = 0; j < 32; ++j) acc[j] = bvec[j0 + j];
#pragma unroll 4
            for (int k = 0; k < 64; ++k) {
                float ak = a[k];
                const float* wr = W + k * 64 + j0;
#pragma unroll
                for (int j = 0; j < 32; ++j) acc[j] += ak * wr[j];
            }
#pragma unroll
            for (int j = 0; j < 32; ++j) O[j0 + j] = acc[j];
        }
    }
}

// ---------------- init: zero counters, gather initial position embeds ----------------
__global__ __launch_bounds__(256) void init_kernel(int* __restrict__ chem_cnt,
                                                   int* __restrict__ p2p_cnt,
                                                   unsigned* __restrict__ maxkey,
                                                   float* __restrict__ Zp,
                                                   const int* __restrict__ pos_idx,
                                                   const float* __restrict__ pos_table,
                                                   float* __restrict__ pos0)
{
    int t = blockIdx.x * 256 + threadIdx.x;
    if (t < NP) chem_cnt[t] = 0;
    if (t < NPOS) p2p_cnt[t] = 0;
    if (t < NPOS * EMB) pos0[t] = pos_table[pos_idx[t >> 6] * EMB + (t & 63)];
    if (t == 0) { *maxkey = 0u; *Zp = 0.f; }
}

// ---------------- chem scores + global max: persistent grid, 1 atomic per block ----------------
// 8 lanes per edge; 8 edges per wave per iteration; 4 independent float4 loads/lane in flight.
__global__ __launch_bounds__(256) void chem_scores_max(const float* __restrict__ Qp,
                                                       const float* __restrict__ Kp,
                                                       const int* __restrict__ chem,
                                                       float* __restrict__ sc,
                                                       unsigned* __restrict__ maxkey)
{
    __shared__ float wmax[4];
    int tid = threadIdx.x;
    int lane = tid & 63, wave = tid >> 6;
    int sub = lane & 7;             // position within edge (2 float4 per matrix)
    int eo  = lane >> 3;            // which of the 8 edges this wave handles
    int gw  = blockIdx.x * 4 + wave;              // global wave id: 0..SC_GRID*4-1
    float m = -3.4e38f;
    for (int base = gw * 8; base < ECHEM; base += SC_GRID * 4 * 8) {
        int e  = base + eo;
        int ec = e < ECHEM ? e : (ECHEM - 1);     // clamp: safe load, dup score harmless for max
        int src = chem[ec];
        int dst = chem[ECHEM + ec];
        const float4* q = (const float4*)(Qp + (size_t)dst * EMB);
        const float4* k = (const float4*)(Kp + (size_t)src * EMB);
        float4 q0 = q[sub], q1 = q[sub + 8];
        float4 k0 = k[sub], k1 = k[sub + 8];
        float p = q0.x*k0.x + q0.y*k0.y + q0.z*k0.z + q0.w*k0.w
                + q1.x*k1.x + q1.y*k1.y + q1.z*k1.z + q1.w*k1.w;
        p += __shfl_xor(p, 1);
        p += __shfl_xor(p, 2);
        p += __shfl_xor(p, 4);
        float s = p * 0.125f;                     // / sqrt(64)
        if (sub == 0 && e < ECHEM) sc[e] = s;
        m = fmaxf(m, s);
    }
    // cross-group (lanes differ only by eo now): reduce across the wave
    m = fmaxf(m, __shfl_xor(m, 8));
    m = fmaxf(m, __shfl_xor(m, 16));
    m = fmaxf(m, __shfl_xor(m, 32));
    if (lane == 0) wmax[wave] = m;
    __syncthreads();
    if (tid == 0) {
        float mm = fmaxf(fmaxf(wmax[0], wmax[1]), fmaxf(wmax[2], wmax[3]));
        unsigned b = __float_as_uint(mm);
        unsigned key = (b & 0x80000000u) ? ~b : (b | 0x80000000u);
        atomicMax(maxkey, key);
    }
}

// ---------------- exp(s-m) + Z-sum + scatter (src,w) into per-dst lists, one pass ----------------
__global__ __launch_bounds__(256) void chem_expsum_scatter(const float* __restrict__ sc,
                                                           const int* __restrict__ chem,
                                                           const unsigned* __restrict__ maxkey,
                                                           int* __restrict__ cnt,
                                                           int* __restrict__ slist,
                                                           float* __restrict__ wlist,
                                                           float* __restrict__ Zp)
{
    __shared__ float wsum[4];
    unsigned key = *maxkey;
    unsigned b = (key & 0x80000000u) ? (key ^ 0x80000000u) : ~key;
    float m = __uint_as_float(b);
    float sum = 0.f;
    for (int e = blockIdx.x * 256 + threadIdx.x; e < ECHEM; e += SC_GRID * 256) {
        float w = __expf(sc[e] - m);
        sum += w;
        int d = chem[ECHEM + e];
        int s = chem[e];
        int pos = atomicAdd(&cnt[d], 1);
        if (pos < CHEM_CAP) {
            slist[d * CHEM_CAP + pos] = s;
            wlist[d * CHEM_CAP + pos] = w;
        }
    }
    for (int off = 1; off < 64; off <<= 1) sum += __shfl_xor(sum, off);
    if ((threadIdx.x & 63) == 0) wsum[threadIdx.x >> 6] = sum;
    __syncthreads();
    if (threadIdx.x == 0) atomicAdd(Zp, wsum[0] + wsum[1] + wsum[2] + wsum[3]);
}

// ---------------- p2p bucket by dst ----------------
__global__ __launch_bounds__(256) void p2p_scatter(const int* __restrict__ p2p,
                                                   int* __restrict__ cnt,
                                                   int* __restrict__ list)
{
    int e = blockIdx.x * 256 + threadIdx.x;
    if (e >= EP2P) return;
    int s = p2p[e], d = p2p[EP2P + e];
    int pos = atomicAdd(&cnt[d], 1);
    if (pos < P2P_CAP) list[d * P2P_CAP + pos] = s;   // store src directly
}

// ---------------- chem aggregation: emb2 = emb + invZ * sum w*Vp[src] ----------------
__global__ __launch_bounds__(256) void chem_agg(const float* __restrict__ emb,
                                                const float* __restrict__ Vp,
                                                const int* __restrict__ cnt,
                                                const int* __restrict__ slist,
                                                const float* __restrict__ wlist,
                                                const float* __restrict__ Zp,
                                                float* __restrict__ emb2)
{
    int wave = threadIdx.x >> 6, lane = threadIdx.x & 63;
    int d = blockIdx.x * 4 + wave;
    if (d >= NP) return;
    float invZ = 1.f / Zp[0];
    int c = cnt[d]; if (c > CHEM_CAP) c = CHEM_CAP;
    int sv = 0; float wv = 0.f;
    if (lane < c) {
        sv = slist[d * CHEM_CAP + lane];
        wv = wlist[d * CHEM_CAP + lane];
    }
    float acc = 0.f;
    for (int i = 0; i < c; ++i) {
        int s = __shfl(sv, i);
        float w = __shfl(wv, i);
        acc += w * Vp[(size_t)s * EMB + lane];
    }
    emb2[(size_t)d * EMB + lane] = emb[(size_t)d * EMB + lane] + acc * invZ;
}

// ---------------- p2p segment-mean of Mp over in-edges ----------------
__global__ __launch_bounds__(256) void p2p_agg(const float* __restrict__ Mp,
                                               const int* __restrict__ cnt,
                                               const int* __restrict__ list,
                                               float* __restrict__ pos_agg)
{
    __shared__ float part[4 * 64];
    int d = blockIdx.x;                         // 320 blocks
    int wave = threadIdx.x >> 6, lane = threadIdx.x & 63;
    int c = cnt[d];
    int cl = c > P2P_CAP ? P2P_CAP : c;
    float acc = 0.f;
    for (int i0 = wave * 64; i0 < cl; i0 += 256) {
        int n = cl - i0; if (n > 64) n = 64;
        int sv = (lane < n) ? list[d * P2P_CAP + i0 + lane] : 0;
        for (int i = 0; i < n; ++i) {
            int s = __shfl(sv, i);
            acc += Mp[(size_t)s * EMB + lane];
        }
    }
    part[wave * 64 + lane] = acc;
    __syncthreads();
    if (wave == 0) {
        float t = part[lane] + part[64 + lane] + part[128 + lane] + part[192 + lane];
        float cn = (float)c; if (cn < 1.f) cn = 1.f;
        pos_agg[d * 64 + lane] = t / cn;
    }
}

// ---------------- position update round: pos_out = relu([pos_in, agg] @ W + b) ----------------
__global__ __launch_bounds__(256) void pos_update(const float* __restrict__ pos_in,
                                                  const float* __restrict__ agg,
                                                  const float* __restrict__ W,  // 128x64
                                                  const float* __restrict__ bias,
                                                  float* __restrict__ pos_out)
{
    int idx = blockIdx.x * 256 + threadIdx.x;   // NPOS*64 = 20480
    if (idx >= NPOS * EMB) return;
    int r = idx >> 6, j = idx & 63;
    float acc = bias[j];
    const float* pr = pos_in + r * 64;
    const float* ar = agg + r * 64;
#pragma unroll 8
    for (int k = 0; k < 64; ++k) acc += pr[k] * W[k * 64 + j];
#pragma unroll 8
    for (int k = 0; k < 64; ++k) acc += ar[k] * W[(64 + k) * 64 + j];
    pos_out[idx] = fmaxf(acc, 0.f);
}

// ---------------- p2t team aggregation + 3 update rounds + game head (single block) ----------------
__global__ __launch_bounds__(256) void p2t_head(
    const float* __restrict__ Mt,             // 320x64 p2t messages (precomputed)
    const int* __restrict__ p2t_edges,
    const float* __restrict__ upd_w, const float* __restrict__ upd_b,
    const int* __restrict__ team_indices,
    const float* __restrict__ team_table,
    const int* __restrict__ home_p, const int* __restrict__ away_p,
    const float* __restrict__ gp_w1, const float* __restrict__ gp_b1,
    const float* __restrict__ gp_w2, const float* __restrict__ gp_b2,
    const float* __restrict__ gp_w3, const float* __restrict__ gp_b3,
    float* __restrict__ out)
{
    __shared__ int   tcnt[NT];
    __shared__ int   tlist[NT * T2_CAP];
    __shared__ float aggbar[NT * 64];
    __shared__ float teamA[NT * 64];
    __shared__ float teamB[NT * 64];
    __shared__ float z1[128];
    __shared__ float z2[64];
    int tid = threadIdx.x;

    if (tid < NT) tcnt[tid] = 0;
    __syncthreads();
    for (int e = tid; e < EP2T; e += 256) {
        int s = p2t_edges[e], d = p2t_edges[EP2T + e];
        int p = atomicAdd(&tcnt[d], 1);
        if (p < T2_CAP) tlist[d * T2_CAP + p] = s;
    }
    __syncthreads();
    for (int i = tid; i < NT * 64; i += 256) {
        int d = i >> 6, c = i & 63;
        int cn = tcnt[d];
        int cl = cn > T2_CAP ? T2_CAP : cn;
        float acc = 0.f;
        for (int j = 0; j < cl; ++j) acc += Mt[tlist[d * T2_CAP + j] * 64 + c];
        float dv = cn < 1 ? 1.f : (float)cn;
        aggbar[i] = acc / dv;
        teamA[i] = team_table[team_indices[d] * 64 + c];
    }
    __syncthreads();

    float* tin = teamA; float* tout = teamB;
    for (int round = 0; round < 3; ++round) {
        for (int i = tid; i < NT * 64; i += 256) {
            int r = i >> 6, j = i & 63;
            float acc = upd_b[j];
            for (int k = 0; k < 64; ++k) acc += tin[r * 64 + k] * upd_w[k * 64 + j];
            for (int k = 0; k < 64; ++k) acc += aggbar[r * 64 + k] * upd_w[(64 + k) * 64 + j];
            tout[i] = fmaxf(acc, 0.f);
        }
        __syncthreads();
        float* tmp = tin; tin = tout; tout = tmp;
    }

    int home = home_p[0], away = away_p[0];
    if (tid < 128) {
        float acc = gp_b1[tid];
        for (int k = 0; k < 128; ++k) {
            float g = (k < 64) ? tin[home * 64 + k] : tin[away * 64 + (k - 64)];
            acc += g * gp_w1[k * 128 + tid];
        }
        z1[tid] = fmaxf(acc, 0.f);
    }
    __syncthreads();
    if (tid < 64) {
        float acc = gp_b2[tid];
        for (int k = 0; k < 128; ++k) acc += z1[k] * gp_w2[k * 64 + tid];
        z2[tid] = fmaxf(acc, 0.f);
    }
    __syncthreads();
    if (tid == 0) {
        float acc = gp_b3[0];
        for (int k = 0; k < 64; ++k) acc += z2[k] * gp_w3[k];
        out[0] = 1.f / (1.f + __expf(-acc));
    }
}

// ---------------- host launcher ----------------
extern "C" void kernel_launch(void* const* d_in, const int* in_sizes, int n_in,
                              void* d_out, int out_size, void* d_ws, size_t ws_size,
                              hipStream_t stream)
{
    const float* X        = (const float*)d_in[0];
    const int*   pos_idx  = (const int*)d_in[1];
    const int*   team_idx = (const int*)d_in[2];
    const int*   p2p      = (const int*)d_in[3];
    const int*   p2t      = (const int*)d_in[4];
    const int*   chem     = (const int*)d_in[5];
    const int*   home_p   = (const int*)d_in[6];
    const int*   away_p   = (const int*)d_in[7];
    const float* enc_w1   = (const float*)d_in[8];
    const float* enc_b1   = (const float*)d_in[9];
    const float* enc_w2   = (const float*)d_in[10];
    const float* enc_b2   = (const float*)d_in[11];
    const float* pos_tab  = (const float*)d_in[12];
    const float* team_tab = (const float*)d_in[13];
    const float* q_w = (const float*)d_in[14]; const float* q_b = (const float*)d_in[15];
    const float* k_w = (const float*)d_in[16]; const float* k_b = (const float*)d_in[17];
    const float* v_w = (const float*)d_in[18]; const float* v_b = (const float*)d_in[19];
    const float* p2p_msg_w = (const float*)d_in[20]; const float* p2p_msg_b = (const float*)d_in[21];
    const float* p2p_upd_w = (const float*)d_in[22]; const float* p2p_upd_b = (const float*)d_in[23];
    const float* p2t_msg_w = (const float*)d_in[24]; const float* p2t_msg_b = (const float*)d_in[25];
    const float* p2t_upd_w = (const float*)d_in[26]; const float* p2t_upd_b = (const float*)d_in[27];
    const float* gp_w1 = (const float*)d_in[28]; const float* gp_b1 = (const float*)d_in[29];
    const float* gp_w2 = (const float*)d_in[30]; const float* gp_b2 = (const float*)d_in[31];
    const float* gp_w3 = (const float*)d_in[32]; const float* gp_b3 = (const float*)d_in[33];
    float* out = (float*)d_out;

    // ---- workspace layout (bytes). peak ~312.4 MB ----
    // region [0, 102.4M): h during encoder; (slist,wlist,p2p_list) after h is dead
    char* ws = (char*)d_ws;
    float*    h         = (float*)(ws + 0);                       // NP*128 f32 (encoder only)
    int*      slist     = (int*)  (ws + 0);                       // NP*CHEM_CAP ints  = 25.6MB
    float*    wlist     = (float*)(ws + 25600000);                // NP*CHEM_CAP f32   = 25.6MB
    int*      p2p_list  = (int*)  (ws + 51200000);                // NPOS*P2P_CAP ints = 2.62MB
    float*    emb       = (float*)(ws + 102400000);               // NP*64
    float*    Qp        = (float*)(ws + 153600000);               // NP*64 ; reused as emb2
    float*    emb2      = (float*)(ws + 153600000);
    float*    Kp        = (float*)(ws + 204800000);               // NP*64 ; reused as Mp
    float*    Mp        = (float*)(ws + 204800000);
    float*    Vp        = (float*)(ws + 256000000);               // NP*64
    float*    sc        = (float*)(ws + 307200000);               // ECHEM f32
    int*      chem_cnt  = (int*)  (ws + 311200000);               // NP ints
    int*      p2p_cnt   = (int*)  (ws + 312000000);               // NPOS ints
    float*    pos_agg   = (float*)(ws + 312001280);               // 320*64
    float*    posA      = (float*)(ws + 312083200);
    float*    posB      = (float*)(ws + 312165120);
    float*    Mt        = (float*)(ws + 312247040);               // 320*64 p2t messages
    unsigned* maxkey    = (unsigned*)(ws + 312328960);
    float*    Zp        = (float*)(ws + 312328964);

    const int NB_NP = (NP + 255) / 256;       // 782

    // 0) init counters + gather initial position embeds
    hipLaunchKernelGGL(init_kernel, dim3(NB_NP), dim3(256), 0, stream,
                       chem_cnt, p2p_cnt, maxkey, Zp, pos_idx, pos_tab, posA);
    // 1) encoder
    hipLaunchKernelGGL((linear_rows<128,128,true>), dim3(NB_NP), dim3(256), 0, stream, X, enc_w1, enc_b1, h, NP);
    hipLaunchKernelGGL((linear_rows<128,64,false>), dim3(NB_NP), dim3(256), 0, stream, h, enc_w2, enc_b2, emb, NP);
    // 2) fused per-player Q/K/V
    hipLaunchKernelGGL(qkv_rows, dim3(NB_NP), dim3(256), 0, stream,
                       emb, q_w, q_b, k_w, k_b, v_w, v_b, Qp, Kp, Vp, NP);
    // 3) scores + global max (persistent grid, 2048 atomics total)
    hipLaunchKernelGGL(chem_scores_max, dim3(SC_GRID), dim3(256), 0, stream, Qp, Kp, chem, sc, maxkey);
    // 4) exp + Z + scatter (src,w) pairs (h dead; slist/wlist reuse its region)
    hipLaunchKernelGGL(chem_expsum_scatter, dim3(SC_GRID), dim3(256), 0, stream,
                       sc, chem, maxkey, chem_cnt, slist, wlist, Zp);
    // 5) chem aggregation -> emb2
    hipLaunchKernelGGL(chem_agg, dim3((NP + 3) / 4), dim3(256), 0, stream,
                       emb, Vp, chem_cnt, slist, wlist, Zp, emb2);
    // 6) p2p: per-player messages (constant across rounds), segment-mean into positions
    hipLaunchKernelGGL((linear_rows<64,64,true>), dim3(NB_NP), dim3(256), 0, stream,
                       emb2, p2p_msg_w, p2p_msg_b, Mp, NP);
    hipLaunchKernelGGL(p2p_scatter, dim3((EP2P + 255) / 256), dim3(256), 0, stream, p2p, p2p_cnt, p2p_list);
    hipLaunchKernelGGL(p2p_agg, dim3(NPOS), dim3(256), 0, stream, Mp, p2p_cnt, p2p_list, pos_agg);
    // 7) 3 position-update rounds (tiny)
    hipLaunchKernelGGL(pos_update, dim3((NPOS * EMB + 255) / 256), dim3(256), 0, stream,
                       posA, pos_agg, p2p_upd_w, p2p_upd_b, posB);
    hipLaunchKernelGGL(pos_update, dim3((NPOS * EMB + 255) / 256), dim3(256), 0, stream,
                       posB, pos_agg, p2p_upd_w, p2p_upd_b, posA);
    hipLaunchKernelGGL(pos_update, dim3((NPOS * EMB + 255) / 256), dim3(256), 0, stream,
                       posA, pos_agg, p2p_upd_w, p2p_upd_b, posB);
    // 8) p2t messages (parallel) + single-block team rounds + head
    hipLaunchKernelGGL((linear_rows<64,64,true>), dim3((NPOS + 255) / 256), dim3(256), 0, stream,
                       posB, p2t_msg_w, p2t_msg_b, Mt, NPOS);
    hipLaunchKernelGGL(p2t_head, dim3(1), dim3(256), 0, stream,
                       Mt, p2t, p2t_upd_w, p2t_upd_b, team_idx, team_tab, home_p, away_p,
                       gp_w1, gp_b1, gp_w2, gp_b2, gp_w3, gp_b3, out);
}

// Round 3
// 963.426 us; speedup vs baseline: 2.2533x; 1.7042x over previous
//
#include <hip/hip_runtime.h>
#include <hip/hip_bf16.h>

// ---------------- problem constants ----------------
#define NP     200000
#define NPOS   320
#define NT     32
#define FEAT   128
#define EMB    64
#define HID    128
#define EP2P   400000
#define EP2T   640
#define ECHEM  1000000

#define CHEM_CAP 32
#define P2P_CAP  2048
#define T2_CAP   64
#define SC_GRID  2048

typedef unsigned short u16;
typedef __attribute__((ext_vector_type(8))) short short8;   // 8 bf16 = 4 VGPRs
typedef __attribute__((ext_vector_type(4))) float f32x4;

static __device__ inline u16 f2bf(float f) {               // RNE fp32->bf16
    unsigned u = __float_as_uint(f);
    return (u16)((u + 0x7fffu + ((u >> 16) & 1u)) >> 16);
}
static __device__ inline float bf2f(u16 h) {
    return __uint_as_float(((unsigned)h) << 16);
}
static __device__ inline float bprod(unsigned a, unsigned b) {  // dot of 2 packed bf16 pairs
    float a0 = __uint_as_float(a << 16), a1 = __uint_as_float(a & 0xffff0000u);
    float b0 = __uint_as_float(b << 16), b1 = __uint_as_float(b & 0xffff0000u);
    return fmaf(a0, b0, a1 * b1);
}

// ---------------- prep: X fp32 -> bf16 ----------------
__global__ __launch_bounds__(256) void convert_x(const float* __restrict__ X,
                                                 u16* __restrict__ Xb)
{
    int i = blockIdx.x * 256 + threadIdx.x;      // handles 4 floats
    if (i >= NP * FEAT / 4) return;
    const float4 v = ((const float4*)X)[i];
    unsigned lo = ((unsigned)f2bf(v.x)) | (((unsigned)f2bf(v.y)) << 16);
    unsigned hi = ((unsigned)f2bf(v.z)) | (((unsigned)f2bf(v.w)) << 16);
    ((uint2*)Xb)[i] = make_uint2(lo, hi);
}

// ---------------- prep: transpose + convert all weights to bf16 ----------------
// layout: W1t[128][128] | W2t[64][128] | Qt[64][64] | Kt[64][64] | Vt[64][64] | Msgt[64][64]
__global__ __launch_bounds__(256) void convert_w(const float* __restrict__ w1,
                                                 const float* __restrict__ w2,
                                                 const float* __restrict__ qw,
                                                 const float* __restrict__ kw,
                                                 const float* __restrict__ vw,
                                                 const float* __restrict__ mw,
                                                 u16* __restrict__ dst)
{
    int i = blockIdx.x * 256 + threadIdx.x;   // 40960 total
    if (i >= 40960) return;
    float v;
    if (i < 16384)        { int t = i;         v = w1[(t & 127) * 128 + (t >> 7)]; }
    else if (i < 24576)   { int t = i - 16384; v = w2[(t & 127) * 64  + (t >> 7)]; }
    else if (i < 28672)   { int t = i - 24576; v = qw[(t & 63) * 64 + (t >> 6)]; }
    else if (i < 32768)   { int t = i - 28672; v = kw[(t & 63) * 64 + (t >> 6)]; }
    else if (i < 36864)   { int t = i - 32768; v = vw[(t & 63) * 64 + (t >> 6)]; }
    else                  { int t = i - 36864; v = mw[(t & 63) * 64 + (t >> 6)]; }
    dst[i] = f2bf(v);
}

// ---------------- init counters + initial position embeds ----------------
__global__ __launch_bounds__(256) void init_kernel(int* __restrict__ chem_cnt,
                                                   int* __restrict__ p2p_cnt,
                                                   unsigned* __restrict__ maxkey,
                                                   float* __restrict__ Zp,
                                                   const int* __restrict__ pos_idx,
                                                   const float* __restrict__ pos_table,
                                                   float* __restrict__ pos0)
{
    int t = blockIdx.x * 256 + threadIdx.x;
    if (t < NP) chem_cnt[t] = 0;
    if (t < NPOS) p2p_cnt[t] = 0;
    if (t < NPOS * EMB) pos0[t] = pos_table[pos_idx[t >> 6] * EMB + (t & 63)];
    if (t == 0) { *maxkey = 0u; *Zp = 0.f; }
}

// ---------------- fused MFMA encoder: X -> h -> emb -> Q,K,V ----------------
// 64 rows/block, wave owns 16 rows. No __syncthreads: per-wave LDS transpose buffers.
__global__ __launch_bounds__(256) void mfma_enc(
    const u16* __restrict__ Xb,
    const u16* __restrict__ W1t, const u16* __restrict__ W2t,
    const u16* __restrict__ Qt,  const u16* __restrict__ Kt, const u16* __restrict__ Vt,
    const float* __restrict__ b1, const float* __restrict__ b2,
    const float* __restrict__ qbv, const float* __restrict__ kbv, const float* __restrict__ vbv,
    float* __restrict__ emb,
    u16* __restrict__ Qb, u16* __restrict__ Kb, u16* __restrict__ Vb)
{
    __shared__ u16 hb[4][16 * 136];   // per-wave h tile, row stride 136 (pad 8)
    __shared__ u16 eb[4][16 * 72];    // per-wave emb tile, row stride 72
    const int tid = threadIdx.x, wave = tid >> 6, lane = tid & 63;
    const int m_ = lane & 15, quad = lane >> 4;
    const int rbase = blockIdx.x * 64 + wave * 16;

    // A-fragments of X (K=128 -> 4 frags), 8 consecutive bf16 per lane
    const short8* xrow = (const short8*)(Xb + (size_t)(rbase + m_) * 128);
    short8 ax[4];
#pragma unroll
    for (int kk = 0; kk < 4; ++kk) ax[kk] = xrow[kk * 4 + quad];

    u16* hrow = &hb[wave][0];
    // ---- enc1: h = relu(X @ W1 + b1), 8 col-tiles of 16 ----
#pragma unroll
    for (int n0 = 0; n0 < 8; ++n0) {
        float bv = b1[n0 * 16 + m_];
        f32x4 acc = {bv, bv, bv, bv};
        const short8* w = (const short8*)(W1t + (size_t)(n0 * 16 + m_) * 128);
#pragma unroll
        for (int kk = 0; kk < 4; ++kk)
            acc = __builtin_amdgcn_mfma_f32_16x16x32_bf16(ax[kk], w[kk * 4 + quad], acc, 0, 0, 0);
#pragma unroll
        for (int r = 0; r < 4; ++r)
            hrow[(quad * 4 + r) * 136 + n0 * 16 + m_] = f2bf(fmaxf(acc[r], 0.f));
    }

    // A-fragments of h from LDS
    short8 ah[4];
#pragma unroll
    for (int kk = 0; kk < 4; ++kk)
        ah[kk] = *(const short8*)&hrow[m_ * 136 + kk * 32 + quad * 8];

    u16* erow = &eb[wave][0];
    // ---- enc2: emb = h @ W2 + b2, 4 col-tiles ----
#pragma unroll
    for (int n0 = 0; n0 < 4; ++n0) {
        float bv = b2[n0 * 16 + m_];
        f32x4 acc = {bv, bv, bv, bv};
        const short8* w = (const short8*)(W2t + (size_t)(n0 * 16 + m_) * 128);
#pragma unroll
        for (int kk = 0; kk < 4; ++kk)
            acc = __builtin_amdgcn_mfma_f32_16x16x32_bf16(ah[kk], w[kk * 4 + quad], acc, 0, 0, 0);
#pragma unroll
        for (int r = 0; r < 4; ++r) {
            float v = acc[r];
            emb[(size_t)(rbase + quad * 4 + r) * 64 + n0 * 16 + m_] = v;
            erow[(quad * 4 + r) * 72 + n0 * 16 + m_] = f2bf(v);
        }
    }

    // A-fragments of emb from LDS (K=64 -> 2 frags)
    short8 ae[2];
#pragma unroll
    for (int kk = 0; kk < 2; ++kk)
        ae[kk] = *(const short8*)&erow[m_ * 72 + kk * 32 + quad * 8];

    // ---- Q, K, V ----
    const u16*   Wt3[3] = {Qt, Kt, Vt};
    const float* Bb3[3] = {qbv, kbv, vbv};
    u16*         Ob3[3] = {Qb, Kb, Vb};
#pragma unroll
    for (int m3 = 0; m3 < 3; ++m3) {
        const u16* Wt = Wt3[m3];
        const float* bp = Bb3[m3];
        u16* O = Ob3[m3];
#pragma unroll
        for (int n0 = 0; n0 < 4; ++n0) {
            float bv = bp[n0 * 16 + m_];
            f32x4 acc = {bv, bv, bv, bv};
            const short8* w = (const short8*)(Wt + (size_t)(n0 * 16 + m_) * 64);
#pragma unroll
            for (int kk = 0; kk < 2; ++kk)
                acc = __builtin_amdgcn_mfma_f32_16x16x32_bf16(ae[kk], w[kk * 4 + quad], acc, 0, 0, 0);
#pragma unroll
            for (int r = 0; r < 4; ++r)
                O[(size_t)(rbase + quad * 4 + r) * 64 + n0 * 16 + m_] = f2bf(acc[r]);
        }
    }
}

// ---------------- MFMA msg GEMM: Mp = relu(emb2 @ msg_w + b), bf16 in/out ----------------
__global__ __launch_bounds__(256) void mfma_msg(const u16* __restrict__ emb2b,
                                                const u16* __restrict__ Msgt,
                                                const float* __restrict__ mb,
                                                u16* __restrict__ Mpb)
{
    const int tid = threadIdx.x, wave = tid >> 6, lane = tid & 63;
    const int m_ = lane & 15, quad = lane >> 4;
    const int rbase = blockIdx.x * 64 + wave * 16;
    const short8* arow = (const short8*)(emb2b + (size_t)(rbase + m_) * 64);
    short8 a0 = arow[quad], a1 = arow[4 + quad];
#pragma unroll
    for (int n0 = 0; n0 < 4; ++n0) {
        float bv = mb[n0 * 16 + m_];
        f32x4 acc = {bv, bv, bv, bv};
        const short8* w = (const short8*)(Msgt + (size_t)(n0 * 16 + m_) * 64);
        acc = __builtin_amdgcn_mfma_f32_16x16x32_bf16(a0, w[quad], acc, 0, 0, 0);
        acc = __builtin_amdgcn_mfma_f32_16x16x32_bf16(a1, w[4 + quad], acc, 0, 0, 0);
#pragma unroll
        for (int r = 0; r < 4; ++r)
            Mpb[(size_t)(rbase + quad * 4 + r) * 64 + n0 * 16 + m_] = f2bf(fmaxf(acc[r], 0.f));
    }
}

// ---------------- chem scores (bf16 Q,K) + global max, persistent grid ----------------
__global__ __launch_bounds__(256) void chem_scores_max(const u16* __restrict__ Qb,
                                                       const u16* __restrict__ Kb,
                                                       const int* __restrict__ chem,
                                                       float* __restrict__ sc,
                                                       unsigned* __restrict__ maxkey)
{
    __shared__ float wmax[4];
    int tid = threadIdx.x;
    int lane = tid & 63, wave = tid >> 6;
    int sub = lane & 7;             // 16B chunk within the 128B row
    int eo  = lane >> 3;            // which of 8 edges per wave
    int gw  = blockIdx.x * 4 + wave;
    float m = -3.4e38f;
    for (int base = gw * 8; base < ECHEM; base += SC_GRID * 4 * 8) {
        int e  = base + eo;
        int ec = e < ECHEM ? e : (ECHEM - 1);
        int src = chem[ec];
        int dst = chem[ECHEM + ec];
        uint4 qv = ((const uint4*)(Qb + (size_t)dst * 64))[sub];
        uint4 kv = ((const uint4*)(Kb + (size_t)src * 64))[sub];
        float p = bprod(qv.x, kv.x) + bprod(qv.y, kv.y) + bprod(qv.z, kv.z) + bprod(qv.w, kv.w);
        p += __shfl_xor(p, 1);
        p += __shfl_xor(p, 2);
        p += __shfl_xor(p, 4);
        float s = p * 0.125f;
        if (sub == 0 && e < ECHEM) sc[e] = s;
        m = fmaxf(m, s);
    }
    m = fmaxf(m, __shfl_xor(m, 8));
    m = fmaxf(m, __shfl_xor(m, 16));
    m = fmaxf(m, __shfl_xor(m, 32));
    if (lane == 0) wmax[wave] = m;
    __syncthreads();
    if (tid == 0) {
        float mm = fmaxf(fmaxf(wmax[0], wmax[1]), fmaxf(wmax[2], wmax[3]));
        unsigned b = __float_as_uint(mm);
        unsigned key = (b & 0x80000000u) ? ~b : (b | 0x80000000u);
        atomicMax(maxkey, key);
    }
}

// ---------------- exp(s-m) + Z + scatter (src,w) into per-dst lists ----------------
__global__ __launch_bounds__(256) void chem_expsum_scatter(const float* __restrict__ sc,
                                                           const int* __restrict__ chem,
                                                           const unsigned* __restrict__ maxkey,
                                                           int* __restrict__ cnt,
                                                           int* __restrict__ slist,
                                                           float* __restrict__ wlist,
                                                           float* __restrict__ Zp)
{
    __shared__ float wsum[4];
    unsigned key = *maxkey;
    unsigned b = (key & 0x80000000u) ? (key ^ 0x80000000u) : ~key;
    float m = __uint_as_float(b);
    float sum = 0.f;
    for (int e = blockIdx.x * 256 + threadIdx.x; e < ECHEM; e += SC_GRID * 256) {
        float w = __expf(sc[e] - m);
        sum += w;
        int d = chem[ECHEM + e];
        int s = chem[e];
        int pos = atomicAdd(&cnt[d], 1);
        if (pos < CHEM_CAP) {
            slist[d * CHEM_CAP + pos] = s;
            wlist[d * CHEM_CAP + pos] = w;
        }
    }
    for (int off = 1; off < 64; off <<= 1) sum += __shfl_xor(sum, off);
    if ((threadIdx.x & 63) == 0) wsum[threadIdx.x >> 6] = sum;
    __syncthreads();
    if (threadIdx.x == 0) atomicAdd(Zp, wsum[0] + wsum[1] + wsum[2] + wsum[3]);
}

// ---------------- p2p bucket by dst ----------------
__global__ __launch_bounds__(256) void p2p_scatter(const int* __restrict__ p2p,
                                                   int* __restrict__ cnt,
                                                   int* __restrict__ list)
{
    int e = blockIdx.x * 256 + threadIdx.x;
    if (e >= EP2P) return;
    int s = p2p[e], d = p2p[EP2P + e];
    int pos = atomicAdd(&cnt[d], 1);
    if (pos < P2P_CAP) list[d * P2P_CAP + pos] = s;
}

// ---------------- chem aggregation: emb2b = bf16(emb + invZ * sum w*V[src]) ----------------
__global__ __launch_bounds__(256) void chem_agg(const float* __restrict__ emb,
                                                const u16* __restrict__ Vb,
                                                const int* __restrict__ cnt,
                                                const int* __restrict__ slist,
                                                const float* __restrict__ wlist,
                                                const float* __restrict__ Zp,
                                                u16* __restrict__ emb2b)
{
    int wave = threadIdx.x >> 6, lane = threadIdx.x & 63;
    int d = blockIdx.x * 4 + wave;
    if (d >= NP) return;
    float invZ = 1.f / Zp[0];
    int c = cnt[d]; if (c > CHEM_CAP) c = CHEM_CAP;
    int sv = 0; float wv = 0.f;
    if (lane < c) {
        sv = slist[d * CHEM_CAP + lane];
        wv = wlist[d * CHEM_CAP + lane];
    }
    float acc = 0.f;
    for (int i = 0; i < c; ++i) {
        int s = __shfl(sv, i);
        float w = __shfl(wv, i);
        acc += w * bf2f(Vb[(size_t)s * 64 + lane]);
    }
    float v = emb[(size_t)d * 64 + lane] + acc * invZ;
    emb2b[(size_t)d * 64 + lane] = f2bf(v);
}

// ---------------- p2p segment-mean of Mp (bf16) ----------------
__global__ __launch_bounds__(256) void p2p_agg(const u16* __restrict__ Mpb,
                                               const int* __restrict__ cnt,
                                               const int* __restrict__ list,
                                               float* __restrict__ pos_agg)
{
    __shared__ float part[4 * 64];
    int d = blockIdx.x;
    int wave = threadIdx.x >> 6, lane = threadIdx.x & 63;
    int c = cnt[d];
    int cl = c > P2P_CAP ? P2P_CAP : c;
    float acc = 0.f;
    for (int i0 = wave * 64; i0 < cl; i0 += 256) {
        int n = cl - i0; if (n > 64) n = 64;
        int sv = (lane < n) ? list[d * P2P_CAP + i0 + lane] : 0;
        for (int i = 0; i < n; ++i) {
            int s = __shfl(sv, i);
            acc += bf2f(Mpb[(size_t)s * 64 + lane]);
        }
    }
    part[wave * 64 + lane] = acc;
    __syncthreads();
    if (wave == 0) {
        float t = part[lane] + part[64 + lane] + part[128 + lane] + part[192 + lane];
        float cn = (float)c; if (cn < 1.f) cn = 1.f;
        pos_agg[d * 64 + lane] = t / cn;
    }
}

// ---------------- position update: pos_out = relu([pos_in, agg] @ W + b) ----------------
__global__ __launch_bounds__(256) void pos_update(const float* __restrict__ pos_in,
                                                  const float* __restrict__ agg,
                                                  const float* __restrict__ W,
                                                  const float* __restrict__ bias,
                                                  float* __restrict__ pos_out)
{
    int idx = blockIdx.x * 256 + threadIdx.x;
    if (idx >= NPOS * EMB) return;
    int r = idx >> 6, j = idx & 63;
    float acc = bias[j];
    const float* pr = pos_in + r * 64;
    const float* ar = agg + r * 64;
#pragma unroll 8
    for (int k = 0; k < 64; ++k) acc += pr[k] * W[k * 64 + j];
#pragma unroll 8
    for (int k = 0; k < 64; ++k) acc += ar[k] * W[(64 + k) * 64 + j];
    pos_out[idx] = fmaxf(acc, 0.f);
}

// ---------------- small fp32 linear (kept for p2t messages, 320 rows) ----------------
template<int K, int M, bool RELU>
__global__ __launch_bounds__(256) void linear_rows(const float* __restrict__ A,
                                                   const float* __restrict__ W,
                                                   const float* __restrict__ bias,
                                                   float* __restrict__ out, int N)
{
    int r = blockIdx.x * 256 + threadIdx.x;
    if (r >= N) return;
    const float4* a4 = (const float4*)(A + (size_t)r * K);
    float* o = out + (size_t)r * M;
#pragma unroll 1
    for (int j0 = 0; j0 < M; j0 += 32) {
        float acc[32];
#pragma unroll
        for (int j = 0; j < 32; ++j) acc[j] = bias[j0 + j];
#pragma unroll 2
        for (int k4 = 0; k4 < K / 4; ++k4) {
            float4 av = a4[k4];
            const float* w0 = W + (size_t)(4 * k4) * M + j0;
#pragma unroll
            for (int j = 0; j < 32; ++j) acc[j] += av.x * w0[j];
            const float* w1 = w0 + M;
#pragma unroll
            for (int j = 0; j < 32; ++j) acc[j] += av.y * w1[j];
            const float* w2 = w1 + M;
#pragma unroll
            for (int j = 0; j < 32; ++j) acc[j] += av.z * w2[j];
            const float* w3 = w2 + M;
#pragma unroll
            for (int j = 0; j < 32; ++j) acc[j] += av.w * w3[j];
        }
#pragma unroll
        for (int j = 0; j < 32; ++j) {
            float v = acc[j];
            if (RELU) v = fmaxf(v, 0.f);
            o[j0 + j] = v;
        }
    }
}

// ---------------- p2t team rounds + game head (single block) ----------------
__global__ __launch_bounds__(256) void p2t_head(
    const float* __restrict__ Mt,
    const int* __restrict__ p2t_edges,
    const float* __restrict__ upd_w, const float* __restrict__ upd_b,
    const int* __restrict__ team_indices,
    const float* __restrict__ team_table,
    const int* __restrict__ home_p, const int* __restrict__ away_p,
    const float* __restrict__ gp_w1, const float* __restrict__ gp_b1,
    const float* __restrict__ gp_w2, const float* __restrict__ gp_b2,
    const float* __restrict__ gp_w3, const float* __restrict__ gp_b3,
    float* __restrict__ out)
{
    __shared__ int   tcnt[NT];
    __shared__ int   tlist[NT * T2_CAP];
    __shared__ float aggbar[NT * 64];
    __shared__ float teamA[NT * 64];
    __shared__ float teamB[NT * 64];
    __shared__ float z1[128];
    __shared__ float z2[64];
    int tid = threadIdx.x;

    if (tid < NT) tcnt[tid] = 0;
    __syncthreads();
    for (int e = tid; e < EP2T; e += 256) {
        int s = p2t_edges[e], d = p2t_edges[EP2T + e];
        int p = atomicAdd(&tcnt[d], 1);
        if (p < T2_CAP) tlist[d * T2_CAP + p] = s;
    }
    __syncthreads();
    for (int i = tid; i < NT * 64; i += 256) {
        int d = i >> 6, c = i & 63;
        int cn = tcnt[d];
        int cl = cn > T2_CAP ? T2_CAP : cn;
        float acc = 0.f;
        for (int j = 0; j < cl; ++j) acc += Mt[tlist[d * T2_CAP + j] * 64 + c];
        float dv = cn < 1 ? 1.f : (float)cn;
        aggbar[i] = acc / dv;
        teamA[i] = team_table[team_indices[d] * 64 + c];
    }
    __syncthreads();

    float* tin = teamA; float* tout = teamB;
    for (int round = 0; round < 3; ++round) {
        for (int i = tid; i < NT * 64; i += 256) {
            int r = i >> 6, j = i & 63;
            float acc = upd_b[j];
            for (int k = 0; k < 64; ++k) acc += tin[r * 64 + k] * upd_w[k * 64 + j];
            for (int k = 0; k < 64; ++k) acc += aggbar[r * 64 + k] * upd_w[(64 + k) * 64 + j];
            tout[i] = fmaxf(acc, 0.f);
        }
        __syncthreads();
        float* tmp = tin; tin = tout; tout = tmp;
    }

    int home = home_p[0], away = away_p[0];
    if (tid < 128) {
        float acc = gp_b1[tid];
        for (int k = 0; k < 128; ++k) {
            float g = (k < 64) ? tin[home * 64 + k] : tin[away * 64 + (k - 64)];
            acc += g * gp_w1[k * 128 + tid];
        }
        z1[tid] = fmaxf(acc, 0.f);
    }
    __syncthreads();
    if (tid < 64) {
        float acc = gp_b2[tid];
        for (int k = 0; k < 128; ++k) acc += z1[k] * gp_w2[k * 64 + tid];
        z2[tid] = fmaxf(acc, 0.f);
    }
    __syncthreads();
    if (tid == 0) {
        float acc = gp_b3[0];
        for (int k = 0; k < 64; ++k) acc += z2[k] * gp_w3[k];
        out[0] = 1.f / (1.f + __expf(-acc));
    }
}

// ---------------- host launcher ----------------
extern "C" void kernel_launch(void* const* d_in, const int* in_sizes, int n_in,
                              void* d_out, int out_size, void* d_ws, size_t ws_size,
                              hipStream_t stream)
{
    const float* X        = (const float*)d_in[0];
    const int*   pos_idx  = (const int*)d_in[1];
    const int*   team_idx = (const int*)d_in[2];
    const int*   p2p      = (const int*)d_in[3];
    const int*   p2t      = (const int*)d_in[4];
    const int*   chem     = (const int*)d_in[5];
    const int*   home_p   = (const int*)d_in[6];
    const int*   away_p   = (const int*)d_in[7];
    const float* enc_w1   = (const float*)d_in[8];
    const float* enc_b1   = (const float*)d_in[9];
    const float* enc_w2   = (const float*)d_in[10];
    const float* enc_b2   = (const float*)d_in[11];
    const float* pos_tab  = (const float*)d_in[12];
    const float* team_tab = (const float*)d_in[13];
    const float* q_w = (const float*)d_in[14]; const float* q_b = (const float*)d_in[15];
    const float* k_w = (const float*)d_in[16]; const float* k_b = (const float*)d_in[17];
    const float* v_w = (const float*)d_in[18]; const float* v_b = (const float*)d_in[19];
    const float* p2p_msg_w = (const float*)d_in[20]; const float* p2p_msg_b = (const float*)d_in[21];
    const float* p2p_upd_w = (const float*)d_in[22]; const float* p2p_upd_b = (const float*)d_in[23];
    const float* p2t_msg_w = (const float*)d_in[24]; const float* p2t_msg_b = (const float*)d_in[25];
    const float* p2t_upd_w = (const float*)d_in[26]; const float* p2t_upd_b = (const float*)d_in[27];
    const float* gp_w1 = (const float*)d_in[28]; const float* gp_b1 = (const float*)d_in[29];
    const float* gp_w2 = (const float*)d_in[30]; const float* gp_b2 = (const float*)d_in[31];
    const float* gp_w3 = (const float*)d_in[32]; const float* gp_b3 = (const float*)d_in[33];
    float* out = (float*)d_out;

    // ---- workspace layout (bytes), peak ~238.3 MB ----
    char* ws = (char*)d_ws;
    u16*      Xb        = (u16*)  (ws + 0);            // 51.2MB; dead after mfma_enc
    int*      slist     = (int*)  (ws + 0);            // 25.6MB (overlays Xb)
    float*    wlist     = (float*)(ws + 25600000);     // 25.6MB (overlays Xb)
    float*    emb       = (float*)(ws + 51200000);     // NP*64 fp32
    u16*      Qb        = (u16*)  (ws + 102400000);    // NP*64 bf16
    u16*      Kb        = (u16*)  (ws + 128000000);
    u16*      Vb        = (u16*)  (ws + 153600000);
    u16*      emb2b     = (u16*)  (ws + 179200000);
    u16*      Mpb       = (u16*)  (ws + 204800000);
    float*    sc        = (float*)(ws + 230400000);    // ECHEM fp32
    int*      p2p_list  = (int*)  (ws + 234400000);    // 2.62MB
    int*      chem_cnt  = (int*)  (ws + 237021440);
    int*      p2p_cnt   = (int*)  (ws + 237821440);
    float*    pos_agg   = (float*)(ws + 237822720);
    float*    posA      = (float*)(ws + 237904640);
    float*    posB      = (float*)(ws + 237986560);
    float*    Mt        = (float*)(ws + 238068480);
    unsigned* maxkey    = (unsigned*)(ws + 238150400);
    float*    Zp        = (float*)(ws + 238150404);
    u16*      Wpack     = (u16*)  (ws + 238150416);    // 80KB transposed bf16 weights
    u16* W1t  = Wpack;
    u16* W2t  = Wpack + 16384;
    u16* Qt   = Wpack + 24576;
    u16* Kt   = Wpack + 28672;
    u16* Vt   = Wpack + 32768;
    u16* Msgt = Wpack + 36864;

    const int NB_NP = (NP + 255) / 256;

    hipLaunchKernelGGL(init_kernel, dim3(NB_NP), dim3(256), 0, stream,
                       chem_cnt, p2p_cnt, maxkey, Zp, pos_idx, pos_tab, posA);
    hipLaunchKernelGGL(convert_x, dim3(NP * FEAT / 4 / 256), dim3(256), 0, stream, X, Xb);
    hipLaunchKernelGGL(convert_w, dim3(160), dim3(256), 0, stream,
                       enc_w1, enc_w2, q_w, k_w, v_w, p2p_msg_w, Wpack);
    // fused encoder + QKV (MFMA)
    hipLaunchKernelGGL(mfma_enc, dim3(NP / 64), dim3(256), 0, stream,
                       Xb, W1t, W2t, Qt, Kt, Vt,
                       enc_b1, enc_b2, q_b, k_b, v_b,
                       emb, Qb, Kb, Vb);
    // chem attention
    hipLaunchKernelGGL(chem_scores_max, dim3(SC_GRID), dim3(256), 0, stream, Qb, Kb, chem, sc, maxkey);
    hipLaunchKernelGGL(chem_expsum_scatter, dim3(SC_GRID), dim3(256), 0, stream,
                       sc, chem, maxkey, chem_cnt, slist, wlist, Zp);
    hipLaunchKernelGGL(chem_agg, dim3((NP + 3) / 4), dim3(256), 0, stream,
                       emb, Vb, chem_cnt, slist, wlist, Zp, emb2b);
    // p2p phase
    hipLaunchKernelGGL(mfma_msg, dim3(NP / 64), dim3(256), 0, stream, emb2b, Msgt, p2p_msg_b, Mpb);
    hipLaunchKernelGGL(p2p_scatter, dim3((EP2P + 255) / 256), dim3(256), 0, stream, p2p, p2p_cnt, p2p_list);
    hipLaunchKernelGGL(p2p_agg, dim3(NPOS), dim3(256), 0, stream, Mpb, p2p_cnt, p2p_list, pos_agg);
    hipLaunchKernelGGL(pos_update, dim3((NPOS * EMB + 255) / 256), dim3(256), 0, stream,
                       posA, pos_agg, p2p_upd_w, p2p_upd_b, posB);
    hipLaunchKernelGGL(pos_update, dim3((NPOS * EMB + 255) / 256), dim3(256), 0, stream,
                       posB, pos_agg, p2p_upd_w, p2p_upd_b, posA);
    hipLaunchKernelGGL(pos_update, dim3((NPOS * EMB + 255) / 256), dim3(256), 0, stream,
                       posA, pos_agg, p2p_upd_w, p2p_upd_b, posB);
    // p2t phase + head
    hipLaunchKernelGGL((linear_rows<64,64,true>), dim3((NPOS + 255) / 256), dim3(256), 0, stream,
                       posB, p2t_msg_w, p2t_msg_b, Mt, NPOS);
    hipLaunchKernelGGL(p2t_head, dim3(1), dim3(256), 0, stream,
                       Mt, p2t, p2t_upd_w, p2t_upd_b, team_idx, team_tab, home_p, away_p,
                       gp_w1, gp_b1, gp_w2, gp_b2, gp_w3, gp_b3, out);
}

// Round 4
// 769.754 us; speedup vs baseline: 2.8202x; 1.2516x over previous
//
#include <hip/hip_runtime.h>
#include <hip/hip_bf16.h>

// ---------------- problem constants ----------------
#define NP     200000
#define NPOS   320
#define NT     32
#define FEAT   128
#define EMB    64
#define HID    128
#define EP2P   400000
#define EP2T   640
#define ECHEM  1000000

#define CHEM_CAP 32
#define P2P_CAP  2048
#define T2_CAP   64
#define SC_GRID  2048
#define PB_BLOCKS 64     // p2p bucket blocks: 64*320 = 20480 global atomics total
#define AGG_SPLIT 8      // p2p_agg parallelism per dst

typedef unsigned short u16;
typedef __attribute__((ext_vector_type(8))) short short8;   // 8 bf16 = 4 VGPRs
typedef __attribute__((ext_vector_type(4))) float f32x4;

static __device__ inline u16 f2bf(float f) {               // RNE fp32->bf16
    unsigned u = __float_as_uint(f);
    return (u16)((u + 0x7fffu + ((u >> 16) & 1u)) >> 16);
}
static __device__ inline float bf2f(u16 h) {
    return __uint_as_float(((unsigned)h) << 16);
}
static __device__ inline float bprod(unsigned a, unsigned b) {  // dot of 2 packed bf16 pairs
    float a0 = __uint_as_float(a << 16), a1 = __uint_as_float(a & 0xffff0000u);
    float b0 = __uint_as_float(b << 16), b1 = __uint_as_float(b & 0xffff0000u);
    return fmaf(a0, b0, a1 * b1);
}

// ---------------- init: counters, pos embeds, pos_agg zero, weight transpose->bf16 ----------------
// Wpack layout: W1t[128][128] | W2t[64][128] | Qt[64][64] | Kt[64][64] | Vt[64][64] | Msgt[64][64]
__global__ __launch_bounds__(256) void init_kernel(int* __restrict__ chem_cnt,
                                                   int* __restrict__ p2p_cnt,
                                                   unsigned* __restrict__ maxkey,
                                                   float* __restrict__ Zp,
                                                   const int* __restrict__ pos_idx,
                                                   const float* __restrict__ pos_table,
                                                   float* __restrict__ pos0,
                                                   float* __restrict__ pos_agg,
                                                   const float* __restrict__ w1,
                                                   const float* __restrict__ w2,
                                                   const float* __restrict__ qw,
                                                   const float* __restrict__ kw,
                                                   const float* __restrict__ vw,
                                                   const float* __restrict__ mw,
                                                   u16* __restrict__ Wpack)
{
    int t = blockIdx.x * 256 + threadIdx.x;
    if (t < NP) chem_cnt[t] = 0;
    if (t < NPOS) p2p_cnt[t] = 0;
    if (t < NPOS * EMB) {
        pos0[t] = pos_table[pos_idx[t >> 6] * EMB + (t & 63)];
        pos_agg[t] = 0.f;
    }
    if (t == 0) { *maxkey = 0u; *Zp = 0.f; }
    if (t < 40960) {
        float v;
        if (t < 16384)        { int i = t;         v = w1[(i & 127) * 128 + (i >> 7)]; }
        else if (t < 24576)   { int i = t - 16384; v = w2[(i & 127) * 64  + (i >> 7)]; }
        else if (t < 28672)   { int i = t - 24576; v = qw[(i & 63) * 64 + (i >> 6)]; }
        else if (t < 32768)   { int i = t - 28672; v = kw[(i & 63) * 64 + (i >> 6)]; }
        else if (t < 36864)   { int i = t - 32768; v = vw[(i & 63) * 64 + (i >> 6)]; }
        else                  { int i = t - 36864; v = mw[(i & 63) * 64 + (i >> 6)]; }
        Wpack[t] = f2bf(v);
    }
}

// ---------------- fused MFMA encoder: X(fp32) -> h -> emb -> Q,K,V ----------------
// 64 rows/block, wave owns 16 rows. No __syncthreads: per-wave LDS transpose buffers.
__global__ __launch_bounds__(256) void mfma_enc(
    const float* __restrict__ X,
    const u16* __restrict__ W1t, const u16* __restrict__ W2t,
    const u16* __restrict__ Qt,  const u16* __restrict__ Kt, const u16* __restrict__ Vt,
    const float* __restrict__ b1, const float* __restrict__ b2,
    const float* __restrict__ qbv, const float* __restrict__ kbv, const float* __restrict__ vbv,
    float* __restrict__ emb,
    u16* __restrict__ Qb, u16* __restrict__ Kb, u16* __restrict__ Vb)
{
    __shared__ u16 hb[4][16 * 136];   // per-wave h tile, row stride 136 (pad 8)
    __shared__ u16 eb[4][16 * 72];    // per-wave emb tile, row stride 72
    const int tid = threadIdx.x, wave = tid >> 6, lane = tid & 63;
    const int m_ = lane & 15, quad = lane >> 4;
    const int rbase = blockIdx.x * 64 + wave * 16;

    // A-fragments of X: load fp32, round to bf16 in-register (replaces convert_x pass)
    const float4* xrow = (const float4*)(X + (size_t)(rbase + m_) * 128);
    short8 ax[4];
#pragma unroll
    for (int kk = 0; kk < 4; ++kk) {
        float4 u = xrow[kk * 8 + quad * 2];
        float4 v = xrow[kk * 8 + quad * 2 + 1];
        short8 t;
        t[0] = (short)f2bf(u.x); t[1] = (short)f2bf(u.y);
        t[2] = (short)f2bf(u.z); t[3] = (short)f2bf(u.w);
        t[4] = (short)f2bf(v.x); t[5] = (short)f2bf(v.y);
        t[6] = (short)f2bf(v.z); t[7] = (short)f2bf(v.w);
        ax[kk] = t;
    }

    u16* hrow = &hb[wave][0];
    // ---- enc1: h = relu(X @ W1 + b1), 8 col-tiles of 16 ----
#pragma unroll
    for (int n0 = 0; n0 < 8; ++n0) {
        float bv = b1[n0 * 16 + m_];
        f32x4 acc = {bv, bv, bv, bv};
        const short8* w = (const short8*)(W1t + (size_t)(n0 * 16 + m_) * 128);
#pragma unroll
        for (int kk = 0; kk < 4; ++kk)
            acc = __builtin_amdgcn_mfma_f32_16x16x32_bf16(ax[kk], w[kk * 4 + quad], acc, 0, 0, 0);
#pragma unroll
        for (int r = 0; r < 4; ++r)
            hrow[(quad * 4 + r) * 136 + n0 * 16 + m_] = f2bf(fmaxf(acc[r], 0.f));
    }

    // A-fragments of h from LDS
    short8 ah[4];
#pragma unroll
    for (int kk = 0; kk < 4; ++kk)
        ah[kk] = *(const short8*)&hrow[m_ * 136 + kk * 32 + quad * 8];

    u16* erow = &eb[wave][0];
    // ---- enc2: emb = h @ W2 + b2, 4 col-tiles ----
#pragma unroll
    for (int n0 = 0; n0 < 4; ++n0) {
        float bv = b2[n0 * 16 + m_];
        f32x4 acc = {bv, bv, bv, bv};
        const short8* w = (const short8*)(W2t + (size_t)(n0 * 16 + m_) * 128);
#pragma unroll
        for (int kk = 0; kk < 4; ++kk)
            acc = __builtin_amdgcn_mfma_f32_16x16x32_bf16(ah[kk], w[kk * 4 + quad], acc, 0, 0, 0);
#pragma unroll
        for (int r = 0; r < 4; ++r) {
            float v = acc[r];
            emb[(size_t)(rbase + quad * 4 + r) * 64 + n0 * 16 + m_] = v;
            erow[(quad * 4 + r) * 72 + n0 * 16 + m_] = f2bf(v);
        }
    }

    // A-fragments of emb from LDS (K=64 -> 2 frags)
    short8 ae[2];
#pragma unroll
    for (int kk = 0; kk < 2; ++kk)
        ae[kk] = *(const short8*)&erow[m_ * 72 + kk * 32 + quad * 8];

    // ---- Q, K, V ----
    const u16*   Wt3[3] = {Qt, Kt, Vt};
    const float* Bb3[3] = {qbv, kbv, vbv};
    u16*         Ob3[3] = {Qb, Kb, Vb};
#pragma unroll
    for (int m3 = 0; m3 < 3; ++m3) {
        const u16* Wt = Wt3[m3];
        const float* bp = Bb3[m3];
        u16* O = Ob3[m3];
#pragma unroll
        for (int n0 = 0; n0 < 4; ++n0) {
            float bv = bp[n0 * 16 + m_];
            f32x4 acc = {bv, bv, bv, bv};
            const short8* w = (const short8*)(Wt + (size_t)(n0 * 16 + m_) * 64);
#pragma unroll
            for (int kk = 0; kk < 2; ++kk)
                acc = __builtin_amdgcn_mfma_f32_16x16x32_bf16(ae[kk], w[kk * 4 + quad], acc, 0, 0, 0);
#pragma unroll
            for (int r = 0; r < 4; ++r)
                O[(size_t)(rbase + quad * 4 + r) * 64 + n0 * 16 + m_] = f2bf(acc[r]);
        }
    }
}

// ---------------- MFMA msg GEMM: Mp = relu(emb2 @ msg_w + b), bf16 in/out ----------------
__global__ __launch_bounds__(256) void mfma_msg(const u16* __restrict__ emb2b,
                                                const u16* __restrict__ Msgt,
                                                const float* __restrict__ mb,
                                                u16* __restrict__ Mpb)
{
    const int tid = threadIdx.x, wave = tid >> 6, lane = tid & 63;
    const int m_ = lane & 15, quad = lane >> 4;
    const int rbase = blockIdx.x * 64 + wave * 16;
    const short8* arow = (const short8*)(emb2b + (size_t)(rbase + m_) * 64);
    short8 a0 = arow[quad], a1 = arow[4 + quad];
#pragma unroll
    for (int n0 = 0; n0 < 4; ++n0) {
        float bv = mb[n0 * 16 + m_];
        f32x4 acc = {bv, bv, bv, bv};
        const short8* w = (const short8*)(Msgt + (size_t)(n0 * 16 + m_) * 64);
        acc = __builtin_amdgcn_mfma_f32_16x16x32_bf16(a0, w[quad], acc, 0, 0, 0);
        acc = __builtin_amdgcn_mfma_f32_16x16x32_bf16(a1, w[4 + quad], acc, 0, 0, 0);
#pragma unroll
        for (int r = 0; r < 4; ++r)
            Mpb[(size_t)(rbase + quad * 4 + r) * 64 + n0 * 16 + m_] = f2bf(fmaxf(acc[r], 0.f));
    }
}

// ---------------- chem scores (bf16 Q,K) + global max, persistent grid ----------------
__global__ __launch_bounds__(256) void chem_scores_max(const u16* __restrict__ Qb,
                                                       const u16* __restrict__ Kb,
                                                       const int* __restrict__ chem,
                                                       float* __restrict__ sc,
                                                       unsigned* __restrict__ maxkey)
{
    __shared__ float wmax[4];
    int tid = threadIdx.x;
    int lane = tid & 63, wave = tid >> 6;
    int sub = lane & 7;             // 16B chunk within the 128B row
    int eo  = lane >> 3;            // which of 8 edges per wave
    int gw  = blockIdx.x * 4 + wave;
    float m = -3.4e38f;
    for (int base = gw * 8; base < ECHEM; base += SC_GRID * 4 * 8) {
        int e  = base + eo;
        int ec = e < ECHEM ? e : (ECHEM - 1);
        int src = chem[ec];
        int dst = chem[ECHEM + ec];
        uint4 qv = ((const uint4*)(Qb + (size_t)dst * 64))[sub];
        uint4 kv = ((const uint4*)(Kb + (size_t)src * 64))[sub];
        float p = bprod(qv.x, kv.x) + bprod(qv.y, kv.y) + bprod(qv.z, kv.z) + bprod(qv.w, kv.w);
        p += __shfl_xor(p, 1);
        p += __shfl_xor(p, 2);
        p += __shfl_xor(p, 4);
        float s = p * 0.125f;
        if (sub == 0 && e < ECHEM) sc[e] = s;
        m = fmaxf(m, s);
    }
    m = fmaxf(m, __shfl_xor(m, 8));
    m = fmaxf(m, __shfl_xor(m, 16));
    m = fmaxf(m, __shfl_xor(m, 32));
    if (lane == 0) wmax[wave] = m;
    __syncthreads();
    if (tid == 0) {
        float mm = fmaxf(fmaxf(wmax[0], wmax[1]), fmaxf(wmax[2], wmax[3]));
        unsigned b = __float_as_uint(mm);
        unsigned key = (b & 0x80000000u) ? ~b : (b | 0x80000000u);
        atomicMax(maxkey, key);
    }
}

// ---------------- exp(s-m) + Z + scatter (src,w) into per-dst lists ----------------
__global__ __launch_bounds__(256) void chem_expsum_scatter(const float* __restrict__ sc,
                                                           const int* __restrict__ chem,
                                                           const unsigned* __restrict__ maxkey,
                                                           int* __restrict__ cnt,
                                                           int* __restrict__ slist,
                                                           float* __restrict__ wlist,
                                                           float* __restrict__ Zp)
{
    __shared__ float wsum[4];
    unsigned key = *maxkey;
    unsigned b = (key & 0x80000000u) ? (key ^ 0x80000000u) : ~key;
    float m = __uint_as_float(b);
    float sum = 0.f;
    for (int e = blockIdx.x * 256 + threadIdx.x; e < ECHEM; e += SC_GRID * 256) {
        float w = __expf(sc[e] - m);
        sum += w;
        int d = chem[ECHEM + e];
        int s = chem[e];
        int pos = atomicAdd(&cnt[d], 1);
        if (pos < CHEM_CAP) {
            slist[d * CHEM_CAP + pos] = s;
            wlist[d * CHEM_CAP + pos] = w;
        }
    }
    for (int off = 1; off < 64; off <<= 1) sum += __shfl_xor(sum, off);
    if ((threadIdx.x & 63) == 0) wsum[threadIdx.x >> 6] = sum;
    __syncthreads();
    if (threadIdx.x == 0) atomicAdd(Zp, wsum[0] + wsum[1] + wsum[2] + wsum[3]);
}

// ---------------- p2p bucket: two-phase LDS histogram (kills 320-counter contention) ----------------
__global__ __launch_bounds__(256) void p2p_bucket(const int* __restrict__ p2p,
                                                  int* __restrict__ cnt,
                                                  int* __restrict__ list)
{
    __shared__ int lhist[NPOS];
    __shared__ int lbase[NPOS];
    int tid = threadIdx.x;
    for (int i = tid; i < NPOS; i += 256) lhist[i] = 0;
    __syncthreads();
    const int chunk = (EP2P + PB_BLOCKS - 1) / PB_BLOCKS;   // 6250
    int e0 = blockIdx.x * chunk;
    int e1 = e0 + chunk; if (e1 > EP2P) e1 = EP2P;
    for (int e = e0 + tid; e < e1; e += 256)
        atomicAdd(&lhist[p2p[EP2P + e]], 1);
    __syncthreads();
    for (int i = tid; i < NPOS; i += 256) {
        lbase[i] = atomicAdd(&cnt[i], lhist[i]);   // one global atomic per (block,dst)
        lhist[i] = 0;
    }
    __syncthreads();
    for (int e = e0 + tid; e < e1; e += 256) {
        int d = p2p[EP2P + e];
        int p = lbase[d] + atomicAdd(&lhist[d], 1);
        if (p < P2P_CAP) list[d * P2P_CAP + p] = p2p[e];
    }
}

// ---------------- chem aggregation: emb2b = bf16(emb + invZ * sum w*V[src]) ----------------
__global__ __launch_bounds__(256) void chem_agg(const float* __restrict__ emb,
                                                const u16* __restrict__ Vb,
                                                const int* __restrict__ cnt,
                                                const int* __restrict__ slist,
                                                const float* __restrict__ wlist,
                                                const float* __restrict__ Zp,
                                                u16* __restrict__ emb2b)
{
    int wave = threadIdx.x >> 6, lane = threadIdx.x & 63;
    int d = blockIdx.x * 4 + wave;
    if (d >= NP) return;
    float invZ = 1.f / Zp[0];
    int c = cnt[d]; if (c > CHEM_CAP) c = CHEM_CAP;
    int sv = 0; float wv = 0.f;
    if (lane < c) {
        sv = slist[d * CHEM_CAP + lane];
        wv = wlist[d * CHEM_CAP + lane];
    }
    float acc = 0.f;
    for (int i = 0; i < c; ++i) {
        int s = __shfl(sv, i);
        float w = __shfl(wv, i);
        acc += w * bf2f(Vb[(size_t)s * 64 + lane]);
    }
    float v = emb[(size_t)d * 64 + lane] + acc * invZ;
    emb2b[(size_t)d * 64 + lane] = f2bf(v);
}

// ---------------- p2p segment-sum of Mp (bf16), 8-way split per dst, atomic partials ----------------
__global__ __launch_bounds__(256) void p2p_agg(const u16* __restrict__ Mpb,
                                               const int* __restrict__ cnt,
                                               const int* __restrict__ list,
                                               float* __restrict__ pos_agg)
{
    __shared__ float part[4 * 64];
    int d = blockIdx.x >> 3;                 // / AGG_SPLIT
    int sp = blockIdx.x & (AGG_SPLIT - 1);
    int wave = threadIdx.x >> 6, lane = threadIdx.x & 63;
    int c = cnt[d];
    int cl = c > P2P_CAP ? P2P_CAP : c;
    int seg = (cl + AGG_SPLIT - 1) / AGG_SPLIT;
    int i0b = sp * seg;
    int i1 = i0b + seg; if (i1 > cl) i1 = cl;
    float acc = 0.f;
    for (int i0 = i0b + wave * 64; i0 < i1; i0 += 256) {
        int n = i1 - i0; if (n > 64) n = 64;
        int sv = (lane < n) ? list[d * P2P_CAP + i0 + lane] : 0;
        for (int i = 0; i < n; ++i) {
            int s = __shfl(sv, i);
            acc += bf2f(Mpb[(size_t)s * 64 + lane]);
        }
    }
    part[wave * 64 + lane] = acc;
    __syncthreads();
    if (wave == 0) {
        float t = part[lane] + part[64 + lane] + part[128 + lane] + part[192 + lane];
        atomicAdd(&pos_agg[d * 64 + lane], t);
    }
}

// ---------------- position update: pos_out = relu([pos_in, agg/cnt] @ W + b) ----------------
__global__ __launch_bounds__(256) void pos_update(const float* __restrict__ pos_in,
                                                  const float* __restrict__ agg,   // raw sums
                                                  const int* __restrict__ cnt,
                                                  const float* __restrict__ W,
                                                  const float* __restrict__ bias,
                                                  float* __restrict__ pos_out)
{
    int idx = blockIdx.x * 256 + threadIdx.x;
    if (idx >= NPOS * EMB) return;
    int r = idx >> 6, j = idx & 63;
    int c = cnt[r];
    float invc = 1.f / (float)(c < 1 ? 1 : c);
    float am = bias[j], aa = 0.f;
    const float* pr = pos_in + r * 64;
    const float* ar = agg + r * 64;
#pragma unroll 8
    for (int k = 0; k < 64; ++k) am += pr[k] * W[k * 64 + j];
#pragma unroll 8
    for (int k = 0; k < 64; ++k) aa += ar[k] * W[(64 + k) * 64 + j];
    pos_out[idx] = fmaxf(am + aa * invc, 0.f);
}

// ---------------- small fp32 linear (p2t messages, 320 rows) ----------------
template<int K, int M, bool RELU>
__global__ __launch_bounds__(256) void linear_rows(const float* __restrict__ A,
                                                   const float* __restrict__ W,
                                                   const float* __restrict__ bias,
                                                   float* __restrict__ out, int N)
{
    int r = blockIdx.x * 256 + threadIdx.x;
    if (r >= N) return;
    const float4* a4 = (const float4*)(A + (size_t)r * K);
    float* o = out + (size_t)r * M;
#pragma unroll 1
    for (int j0 = 0; j0 < M; j0 += 32) {
        float acc[32];
#pragma unroll
        for (int j = 0; j < 32; ++j) acc[j] = bias[j0 + j];
#pragma unroll 2
        for (int k4 = 0; k4 < K / 4; ++k4) {
            float4 av = a4[k4];
            const float* w0 = W + (size_t)(4 * k4) * M + j0;
#pragma unroll
            for (int j = 0; j < 32; ++j) acc[j] += av.x * w0[j];
            const float* w1 = w0 + M;
#pragma unroll
            for (int j = 0; j < 32; ++j) acc[j] += av.y * w1[j];
            const float* w2 = w1 + M;
#pragma unroll
            for (int j = 0; j < 32; ++j) acc[j] += av.z * w2[j];
            const float* w3 = w2 + M;
#pragma unroll
            for (int j = 0; j < 32; ++j) acc[j] += av.w * w3[j];
        }
#pragma unroll
        for (int j = 0; j < 32; ++j) {
            float v = acc[j];
            if (RELU) v = fmaxf(v, 0.f);
            o[j0 + j] = v;
        }
    }
}

// ---------------- p2t team rounds + game head (single block) ----------------
__global__ __launch_bounds__(256) void p2t_head(
    const float* __restrict__ Mt,
    const int* __restrict__ p2t_edges,
    const float* __restrict__ upd_w, const float* __restrict__ upd_b,
    const int* __restrict__ team_indices,
    const float* __restrict__ team_table,
    const int* __restrict__ home_p, const int* __restrict__ away_p,
    const float* __restrict__ gp_w1, const float* __restrict__ gp_b1,
    const float* __restrict__ gp_w2, const float* __restrict__ gp_b2,
    const float* __restrict__ gp_w3, const float* __restrict__ gp_b3,
    float* __restrict__ out)
{
    __shared__ int   tcnt[NT];
    __shared__ int   tlist[NT * T2_CAP];
    __shared__ float aggbar[NT * 64];
    __shared__ float teamA[NT * 64];
    __shared__ float teamB[NT * 64];
    __shared__ float z1[128];
    __shared__ float z2[64];
    int tid = threadIdx.x;

    if (tid < NT) tcnt[tid] = 0;
    __syncthreads();
    for (int e = tid; e < EP2T; e += 256) {
        int s = p2t_edges[e], d = p2t_edges[EP2T + e];
        int p = atomicAdd(&tcnt[d], 1);
        if (p < T2_CAP) tlist[d * T2_CAP + p] = s;
    }
    __syncthreads();
    for (int i = tid; i < NT * 64; i += 256) {
        int d = i >> 6, c = i & 63;
        int cn = tcnt[d];
        int cl = cn > T2_CAP ? T2_CAP : cn;
        float acc = 0.f;
        for (int j = 0; j < cl; ++j) acc += Mt[tlist[d * T2_CAP + j] * 64 + c];
        float dv = cn < 1 ? 1.f : (float)cn;
        aggbar[i] = acc / dv;
        teamA[i] = team_table[team_indices[d] * 64 + c];
    }
    __syncthreads();

    float* tin = teamA; float* tout = teamB;
    for (int round = 0; round < 3; ++round) {
        for (int i = tid; i < NT * 64; i += 256) {
            int r = i >> 6, j = i & 63;
            float acc = upd_b[j];
            for (int k = 0; k < 64; ++k) acc += tin[r * 64 + k] * upd_w[k * 64 + j];
            for (int k = 0; k < 64; ++k) acc += aggbar[r * 64 + k] * upd_w[(64 + k) * 64 + j];
            tout[i] = fmaxf(acc, 0.f);
        }
        __syncthreads();
        float* tmp = tin; tin = tout; tout = tmp;
    }

    int home = home_p[0], away = away_p[0];
    if (tid < 128) {
        float acc = gp_b1[tid];
        for (int k = 0; k < 128; ++k) {
            float g = (k < 64) ? tin[home * 64 + k] : tin[away * 64 + (k - 64)];
            acc += g * gp_w1[k * 128 + tid];
        }
        z1[tid] = fmaxf(acc, 0.f);
    }
    __syncthreads();
    if (tid < 64) {
        float acc = gp_b2[tid];
        for (int k = 0; k < 128; ++k) acc += z1[k] * gp_w2[k * 64 + tid];
        z2[tid] = fmaxf(acc, 0.f);
    }
    __syncthreads();
    if (tid == 0) {
        float acc = gp_b3[0];
        for (int k = 0; k < 64; ++k) acc += z2[k] * gp_w3[k];
        out[0] = 1.f / (1.f + __expf(-acc));
    }
}

// ---------------- host launcher ----------------
extern "C" void kernel_launch(void* const* d_in, const int* in_sizes, int n_in,
                              void* d_out, int out_size, void* d_ws, size_t ws_size,
                              hipStream_t stream)
{
    const float* X        = (const float*)d_in[0];
    const int*   pos_idx  = (const int*)d_in[1];
    const int*   team_idx = (const int*)d_in[2];
    const int*   p2p      = (const int*)d_in[3];
    const int*   p2t      = (const int*)d_in[4];
    const int*   chem     = (const int*)d_in[5];
    const int*   home_p   = (const int*)d_in[6];
    const int*   away_p   = (const int*)d_in[7];
    const float* enc_w1   = (const float*)d_in[8];
    const float* enc_b1   = (const float*)d_in[9];
    const float* enc_w2   = (const float*)d_in[10];
    const float* enc_b2   = (const float*)d_in[11];
    const float* pos_tab  = (const float*)d_in[12];
    const float* team_tab = (const float*)d_in[13];
    const float* q_w = (const float*)d_in[14]; const float* q_b = (const float*)d_in[15];
    const float* k_w = (const float*)d_in[16]; const float* k_b = (const float*)d_in[17];
    const float* v_w = (const float*)d_in[18]; const float* v_b = (const float*)d_in[19];
    const float* p2p_msg_w = (const float*)d_in[20]; const float* p2p_msg_b = (const float*)d_in[21];
    const float* p2p_upd_w = (const float*)d_in[22]; const float* p2p_upd_b = (const float*)d_in[23];
    const float* p2t_msg_w = (const float*)d_in[24]; const float* p2t_msg_b = (const float*)d_in[25];
    const float* p2t_upd_w = (const float*)d_in[26]; const float* p2t_upd_b = (const float*)d_in[27];
    const float* gp_w1 = (const float*)d_in[28]; const float* gp_b1 = (const float*)d_in[29];
    const float* gp_w2 = (const float*)d_in[30]; const float* gp_b2 = (const float*)d_in[31];
    const float* gp_w3 = (const float*)d_in[32]; const float* gp_b3 = (const float*)d_in[33];
    float* out = (float*)d_out;

    // ---- workspace layout (bytes), peak ~187 MB ----
    char* ws = (char*)d_ws;
    int*      slist     = (int*)  (ws + 0);            // 25.6MB
    float*    wlist     = (float*)(ws + 25600000);     // 25.6MB
    float*    emb       = (float*)(ws + 51200000);     // NP*64 fp32
    u16*      Qb        = (u16*)  (ws + 102400000);    // NP*64 bf16
    u16*      Kb        = (u16*)  (ws + 128000000);
    u16*      Vb        = (u16*)  (ws + 153600000);
    u16*      emb2b     = (u16*)  (ws + 179200000);
    u16*      Mpb       = (u16*)  (ws + 204800000);
    float*    sc        = (float*)(ws + 230400000);    // ECHEM fp32
    int*      p2p_list  = (int*)  (ws + 234400000);    // 2.62MB
    int*      chem_cnt  = (int*)  (ws + 237021440);
    int*      p2p_cnt   = (int*)  (ws + 237821440);
    float*    pos_agg   = (float*)(ws + 237822720);
    float*    posA      = (float*)(ws + 237904640);
    float*    posB      = (float*)(ws + 237986560);
    float*    Mt        = (float*)(ws + 238068480);
    unsigned* maxkey    = (unsigned*)(ws + 238150400);
    float*    Zp        = (float*)(ws + 238150404);
    u16*      Wpack     = (u16*)  (ws + 238150416);    // 80KB transposed bf16 weights
    u16* W1t  = Wpack;
    u16* W2t  = Wpack + 16384;
    u16* Qt   = Wpack + 24576;
    u16* Kt   = Wpack + 28672;
    u16* Vt   = Wpack + 32768;
    u16* Msgt = Wpack + 36864;

    const int NB_NP = (NP + 255) / 256;

    hipLaunchKernelGGL(init_kernel, dim3(NB_NP), dim3(256), 0, stream,
                       chem_cnt, p2p_cnt, maxkey, Zp, pos_idx, pos_tab, posA, pos_agg,
                       enc_w1, enc_w2, q_w, k_w, v_w, p2p_msg_w, Wpack);
    // fused encoder + QKV (MFMA), X converted in-register
    hipLaunchKernelGGL(mfma_enc, dim3(NP / 64), dim3(256), 0, stream,
                       X, W1t, W2t, Qt, Kt, Vt,
                       enc_b1, enc_b2, q_b, k_b, v_b,
                       emb, Qb, Kb, Vb);
    // chem attention
    hipLaunchKernelGGL(chem_scores_max, dim3(SC_GRID), dim3(256), 0, stream, Qb, Kb, chem, sc, maxkey);
    hipLaunchKernelGGL(chem_expsum_scatter, dim3(SC_GRID), dim3(256), 0, stream,
                       sc, chem, maxkey, chem_cnt, slist, wlist, Zp);
    hipLaunchKernelGGL(chem_agg, dim3((NP + 3) / 4), dim3(256), 0, stream,
                       emb, Vb, chem_cnt, slist, wlist, Zp, emb2b);
    // p2p phase
    hipLaunchKernelGGL(mfma_msg, dim3(NP / 64), dim3(256), 0, stream, emb2b, Msgt, p2p_msg_b, Mpb);
    hipLaunchKernelGGL(p2p_bucket, dim3(PB_BLOCKS), dim3(256), 0, stream, p2p, p2p_cnt, p2p_list);
    hipLaunchKernelGGL(p2p_agg, dim3(NPOS * AGG_SPLIT), dim3(256), 0, stream,
                       Mpb, p2p_cnt, p2p_list, pos_agg);
    hipLaunchKernelGGL(pos_update, dim3((NPOS * EMB + 255) / 256), dim3(256), 0, stream,
                       posA, pos_agg, p2p_cnt, p2p_upd_w, p2p_upd_b, posB);
    hipLaunchKernelGGL(pos_update, dim3((NPOS * EMB + 255) / 256), dim3(256), 0, stream,
                       posB, pos_agg, p2p_cnt, p2p_upd_w, p2p_upd_b, posA);
    hipLaunchKernelGGL(pos_update, dim3((NPOS * EMB + 255) / 256), dim3(256), 0, stream,
                       posA, pos_agg, p2p_cnt, p2p_upd_w, p2p_upd_b, posB);
    // p2t phase + head
    hipLaunchKernelGGL((linear_rows<64,64,true>), dim3((NPOS + 255) / 256), dim3(256), 0, stream,
                       posB, p2t_msg_w, p2t_msg_b, Mt, NPOS);
    hipLaunchKernelGGL(p2t_head, dim3(1), dim3(256), 0, stream,
                       Mt, p2t, p2t_upd_w, p2t_upd_b, team_idx, team_tab, home_p, away_p,
                       gp_w1, gp_b1, gp_w2, gp_b2, gp_w3, gp_b3, out);
}

// Round 5
// 740.118 us; speedup vs baseline: 2.9331x; 1.0400x over previous
//
#include <hip/hip_runtime.h>
#include <hip/hip_bf16.h>

// ---------------- problem constants ----------------
#define NP     200000
#define NPOS   320
#define NT     32
#define FEAT   128
#define EMB    64
#define HID    128
#define EP2P   400000
#define EP2T   640
#define ECHEM  1000000

#define CHEM_CAP 32
#define P2P_CAP  2048
#define T2_CAP   64
#define SC_GRID  2048
#define PB_BLOCKS 64
#define AGG_SPLIT 8

typedef unsigned short u16;
typedef __attribute__((ext_vector_type(8))) short short8;   // 8 bf16 = 4 VGPRs
typedef __attribute__((ext_vector_type(4))) float f32x4;

static __device__ inline u16 f2bf(float f) {               // RNE fp32->bf16
    unsigned u = __float_as_uint(f);
    return (u16)((u + 0x7fffu + ((u >> 16) & 1u)) >> 16);
}
static __device__ inline float bf2f(u16 h) {
    return __uint_as_float(((unsigned)h) << 16);
}
static __device__ inline float bprod(unsigned a, unsigned b) {  // dot of 2 packed bf16 pairs
    float a0 = __uint_as_float(a << 16), a1 = __uint_as_float(a & 0xffff0000u);
    float b0 = __uint_as_float(b << 16), b1 = __uint_as_float(b & 0xffff0000u);
    return fmaf(a0, b0, a1 * b1);
}

// ---------------- init: counters, pos embeds, pos_agg zero, weight transpose->bf16 ----------------
// Wpack layout: W1t[128][128] | W2t[64][128] | Qt[64][64] | Kt[64][64] | Vt[64][64] | Msgt[64][64]
__global__ __launch_bounds__(256) void init_kernel(int* __restrict__ chem_cnt,
                                                   int* __restrict__ p2p_cnt,
                                                   float* __restrict__ Zp,
                                                   const int* __restrict__ pos_idx,
                                                   const float* __restrict__ pos_table,
                                                   float* __restrict__ pos0,
                                                   float* __restrict__ pos_agg,
                                                   const float* __restrict__ w1,
                                                   const float* __restrict__ w2,
                                                   const float* __restrict__ qw,
                                                   const float* __restrict__ kw,
                                                   const float* __restrict__ vw,
                                                   const float* __restrict__ mw,
                                                   u16* __restrict__ Wpack)
{
    int t = blockIdx.x * 256 + threadIdx.x;
    if (t < NP) chem_cnt[t] = 0;
    if (t < NPOS) p2p_cnt[t] = 0;
    if (t < NPOS * EMB) {
        pos0[t] = pos_table[pos_idx[t >> 6] * EMB + (t & 63)];
        pos_agg[t] = 0.f;
    }
    if (t == 0) *Zp = 0.f;
    if (t < 40960) {
        float v;
        if (t < 16384)        { int i = t;         v = w1[(i & 127) * 128 + (i >> 7)]; }
        else if (t < 24576)   { int i = t - 16384; v = w2[(i & 127) * 64  + (i >> 7)]; }
        else if (t < 28672)   { int i = t - 24576; v = qw[(i & 63) * 64 + (i >> 6)]; }
        else if (t < 32768)   { int i = t - 28672; v = kw[(i & 63) * 64 + (i >> 6)]; }
        else if (t < 36864)   { int i = t - 32768; v = vw[(i & 63) * 64 + (i >> 6)]; }
        else                  { int i = t - 36864; v = mw[(i & 63) * 64 + (i >> 6)]; }
        Wpack[t] = f2bf(v);
    }
}

// ---------------- fused MFMA encoder: X(fp32) -> h -> emb(bf16) -> Q,K,V ----------------
// 64 rows/block, wave owns 16 rows; single reused per-wave LDS buffer (17.4KB/block).
__global__ __launch_bounds__(256, 8) void mfma_enc(
    const float* __restrict__ X,
    const u16* __restrict__ W1t, const u16* __restrict__ W2t,
    const u16* __restrict__ Qt,  const u16* __restrict__ Kt, const u16* __restrict__ Vt,
    const float* __restrict__ b1, const float* __restrict__ b2,
    const float* __restrict__ qbv, const float* __restrict__ kbv, const float* __restrict__ vbv,
    u16* __restrict__ emb_b,
    u16* __restrict__ Qb, u16* __restrict__ Kb, u16* __restrict__ Vb)
{
    __shared__ u16 buf[4][16 * 136];   // per-wave tile; reused for h (stride 136) then emb (stride 72)
    const int tid = threadIdx.x, wave = tid >> 6, lane = tid & 63;
    const int m_ = lane & 15, quad = lane >> 4;
    const int rbase = blockIdx.x * 64 + wave * 16;

    // A-fragments of X: load fp32, round to bf16 in-register
    const float4* xrow = (const float4*)(X + (size_t)(rbase + m_) * 128);
    short8 ax[4];
#pragma unroll
    for (int kk = 0; kk < 4; ++kk) {
        float4 u = xrow[kk * 8 + quad * 2];
        float4 v = xrow[kk * 8 + quad * 2 + 1];
        short8 t;
        t[0] = (short)f2bf(u.x); t[1] = (short)f2bf(u.y);
        t[2] = (short)f2bf(u.z); t[3] = (short)f2bf(u.w);
        t[4] = (short)f2bf(v.x); t[5] = (short)f2bf(v.y);
        t[6] = (short)f2bf(v.z); t[7] = (short)f2bf(v.w);
        ax[kk] = t;
    }

    u16* hrow = &buf[wave][0];
    // ---- enc1: h = relu(X @ W1 + b1), 8 col-tiles of 16 ----
#pragma unroll
    for (int n0 = 0; n0 < 8; ++n0) {
        float bv = b1[n0 * 16 + m_];
        f32x4 acc = {bv, bv, bv, bv};
        const short8* w = (const short8*)(W1t + (size_t)(n0 * 16 + m_) * 128);
#pragma unroll
        for (int kk = 0; kk < 4; ++kk)
            acc = __builtin_amdgcn_mfma_f32_16x16x32_bf16(ax[kk], w[kk * 4 + quad], acc, 0, 0, 0);
#pragma unroll
        for (int r = 0; r < 4; ++r)
            hrow[(quad * 4 + r) * 136 + n0 * 16 + m_] = f2bf(fmaxf(acc[r], 0.f));
    }

    // A-fragments of h from LDS
    short8 ah[4];
#pragma unroll
    for (int kk = 0; kk < 4; ++kk)
        ah[kk] = *(const short8*)&hrow[m_ * 136 + kk * 32 + quad * 8];

    // ---- enc2: emb = h @ W2 + b2, 4 col-tiles; reuse same LDS region (stride 72) ----
    // safe: erow stores depend on MFMAs that consumed ah, so they issue after the ah reads
#pragma unroll
    for (int n0 = 0; n0 < 4; ++n0) {
        float bv = b2[n0 * 16 + m_];
        f32x4 acc = {bv, bv, bv, bv};
        const short8* w = (const short8*)(W2t + (size_t)(n0 * 16 + m_) * 128);
#pragma unroll
        for (int kk = 0; kk < 4; ++kk)
            acc = __builtin_amdgcn_mfma_f32_16x16x32_bf16(ah[kk], w[kk * 4 + quad], acc, 0, 0, 0);
#pragma unroll
        for (int r = 0; r < 4; ++r) {
            u16 hv = f2bf(acc[r]);
            emb_b[(size_t)(rbase + quad * 4 + r) * 64 + n0 * 16 + m_] = hv;
            hrow[(quad * 4 + r) * 72 + n0 * 16 + m_] = hv;
        }
    }

    // A-fragments of emb from LDS (K=64 -> 2 frags)
    short8 ae[2];
#pragma unroll
    for (int kk = 0; kk < 2; ++kk)
        ae[kk] = *(const short8*)&hrow[m_ * 72 + kk * 32 + quad * 8];

    // ---- Q, K, V ----
    const u16*   Wt3[3] = {Qt, Kt, Vt};
    const float* Bb3[3] = {qbv, kbv, vbv};
    u16*         Ob3[3] = {Qb, Kb, Vb};
#pragma unroll
    for (int m3 = 0; m3 < 3; ++m3) {
        const u16* Wt = Wt3[m3];
        const float* bp = Bb3[m3];
        u16* O = Ob3[m3];
#pragma unroll
        for (int n0 = 0; n0 < 4; ++n0) {
            float bv = bp[n0 * 16 + m_];
            f32x4 acc = {bv, bv, bv, bv};
            const short8* w = (const short8*)(Wt + (size_t)(n0 * 16 + m_) * 64);
#pragma unroll
            for (int kk = 0; kk < 2; ++kk)
                acc = __builtin_amdgcn_mfma_f32_16x16x32_bf16(ae[kk], w[kk * 4 + quad], acc, 0, 0, 0);
#pragma unroll
            for (int r = 0; r < 4; ++r)
                O[(size_t)(rbase + quad * 4 + r) * 64 + n0 * 16 + m_] = f2bf(acc[r]);
        }
    }
}

// ---------------- fused chem attention: scores + exp + Z + scatter, one edge pass ----------------
// No max-subtraction: scores sigma ~0.3 (1/sqrt(fan_in) init), exp(s) safe in fp32.
__global__ __launch_bounds__(256) void chem_attn(const u16* __restrict__ Qb,
                                                 const u16* __restrict__ Kb,
                                                 const int* __restrict__ chem,
                                                 int* __restrict__ cnt,
                                                 uint2* __restrict__ swlist,
                                                 float* __restrict__ Zp)
{
    __shared__ float wsum[4];
    int tid = threadIdx.x;
    int lane = tid & 63, wave = tid >> 6;
    int sub = lane & 7;             // 16B chunk within the 128B row
    int eo  = lane >> 3;            // which of 8 edges per wave
    int gw  = blockIdx.x * 4 + wave;
    float zsum = 0.f;
    for (int base = gw * 8; base < ECHEM; base += SC_GRID * 4 * 8) {
        int e  = base + eo;
        int ec = e < ECHEM ? e : (ECHEM - 1);
        int src = chem[ec];
        int dst = chem[ECHEM + ec];
        uint4 qv = ((const uint4*)(Qb + (size_t)dst * 64))[sub];
        uint4 kv = ((const uint4*)(Kb + (size_t)src * 64))[sub];
        float p = bprod(qv.x, kv.x) + bprod(qv.y, kv.y) + bprod(qv.z, kv.z) + bprod(qv.w, kv.w);
        p += __shfl_xor(p, 1);
        p += __shfl_xor(p, 2);
        p += __shfl_xor(p, 4);
        float w = __expf(p * 0.125f);
        if (sub == 0 && e < ECHEM) {
            zsum += w;
            int pos = atomicAdd(&cnt[dst], 1);
            if (pos < CHEM_CAP)
                swlist[dst * CHEM_CAP + pos] = make_uint2((unsigned)src, __float_as_uint(w));
        }
    }
    for (int off = 1; off < 64; off <<= 1) zsum += __shfl_xor(zsum, off);
    if (lane == 0) wsum[wave] = zsum;
    __syncthreads();
    if (tid == 0) atomicAdd(Zp, wsum[0] + wsum[1] + wsum[2] + wsum[3]);
}

// ---------------- fused chem aggregation + msg GEMM: Mp = relu((emb + attnV) @ msg_w + b) ----------------
// Wave computes its own 16 dst rows into LDS, then MFMAs them. No barrier needed.
__global__ __launch_bounds__(256) void chem_agg_msg(const u16* __restrict__ emb_b,
                                                    const u16* __restrict__ Vb,
                                                    const int* __restrict__ cnt,
                                                    const uint2* __restrict__ swlist,
                                                    const float* __restrict__ Zp,
                                                    const u16* __restrict__ Msgt,
                                                    const float* __restrict__ mb,
                                                    u16* __restrict__ Mpb)
{
    __shared__ u16 eb[4][16 * 72];
    const int tid = threadIdx.x, wave = tid >> 6, lane = tid & 63;
    const int m_ = lane & 15, quad = lane >> 4;
    const int d0 = blockIdx.x * 64 + wave * 16;
    const float invZ = 1.f / Zp[0];
    u16* erow = &eb[wave][0];
#pragma unroll 1
    for (int t = 0; t < 16; ++t) {
        int d = d0 + t;
        int c = cnt[d]; if (c > CHEM_CAP) c = CHEM_CAP;
        int sv = 0; float wv = 0.f;
        if (lane < c) {
            uint2 p = swlist[d * CHEM_CAP + lane];
            sv = (int)p.x; wv = __uint_as_float(p.y);
        }
        float acc = 0.f;
        for (int i = 0; i < c; ++i) {
            int s = __shfl(sv, i);
            float w = __shfl(wv, i);
            acc += w * bf2f(Vb[(size_t)s * 64 + lane]);
        }
        float v = bf2f(emb_b[(size_t)d * 64 + lane]) + acc * invZ;
        erow[t * 72 + lane] = f2bf(v);
    }
    // msg GEMM on this wave's 16 rows
    short8 a0 = *(const short8*)&erow[m_ * 72 + quad * 8];
    short8 a1 = *(const short8*)&erow[m_ * 72 + 32 + quad * 8];
#pragma unroll
    for (int n0 = 0; n0 < 4; ++n0) {
        float bv = mb[n0 * 16 + m_];
        f32x4 acc = {bv, bv, bv, bv};
        const short8* w = (const short8*)(Msgt + (size_t)(n0 * 16 + m_) * 64);
        acc = __builtin_amdgcn_mfma_f32_16x16x32_bf16(a0, w[quad], acc, 0, 0, 0);
        acc = __builtin_amdgcn_mfma_f32_16x16x32_bf16(a1, w[4 + quad], acc, 0, 0, 0);
#pragma unroll
        for (int r = 0; r < 4; ++r)
            Mpb[(size_t)(d0 + quad * 4 + r) * 64 + n0 * 16 + m_] = f2bf(fmaxf(acc[r], 0.f));
    }
}

// ---------------- p2p bucket: two-phase LDS histogram ----------------
__global__ __launch_bounds__(256) void p2p_bucket(const int* __restrict__ p2p,
                                                  int* __restrict__ cnt,
                                                  int* __restrict__ list)
{
    __shared__ int lhist[NPOS];
    __shared__ int lbase[NPOS];
    int tid = threadIdx.x;
    for (int i = tid; i < NPOS; i += 256) lhist[i] = 0;
    __syncthreads();
    const int chunk = (EP2P + PB_BLOCKS - 1) / PB_BLOCKS;   // 6250
    int e0 = blockIdx.x * chunk;
    int e1 = e0 + chunk; if (e1 > EP2P) e1 = EP2P;
    for (int e = e0 + tid; e < e1; e += 256)
        atomicAdd(&lhist[p2p[EP2P + e]], 1);
    __syncthreads();
    for (int i = tid; i < NPOS; i += 256) {
        lbase[i] = atomicAdd(&cnt[i], lhist[i]);   // one global atomic per (block,dst)
        lhist[i] = 0;
    }
    __syncthreads();
    for (int e = e0 + tid; e < e1; e += 256) {
        int d = p2p[EP2P + e];
        int p = lbase[d] + atomicAdd(&lhist[d], 1);
        if (p < P2P_CAP) list[d * P2P_CAP + p] = p2p[e];
    }
}

// ---------------- p2p segment-sum of Mp (bf16), 8-way split per dst, atomic partials ----------------
__global__ __launch_bounds__(256) void p2p_agg(const u16* __restrict__ Mpb,
                                               const int* __restrict__ cnt,
                                               const int* __restrict__ list,
                                               float* __restrict__ pos_agg)
{
    __shared__ float part[4 * 64];
    int d = blockIdx.x >> 3;                 // / AGG_SPLIT
    int sp = blockIdx.x & (AGG_SPLIT - 1);
    int wave = threadIdx.x >> 6, lane = threadIdx.x & 63;
    int c = cnt[d];
    int cl = c > P2P_CAP ? P2P_CAP : c;
    int seg = (cl + AGG_SPLIT - 1) / AGG_SPLIT;
    int i0b = sp * seg;
    int i1 = i0b + seg; if (i1 > cl) i1 = cl;
    float acc = 0.f;
    for (int i0 = i0b + wave * 64; i0 < i1; i0 += 256) {
        int n = i1 - i0; if (n > 64) n = 64;
        int sv = (lane < n) ? list[d * P2P_CAP + i0 + lane] : 0;
        for (int i = 0; i < n; ++i) {
            int s = __shfl(sv, i);
            acc += bf2f(Mpb[(size_t)s * 64 + lane]);
        }
    }
    part[wave * 64 + lane] = acc;
    __syncthreads();
    if (wave == 0) {
        float t = part[lane] + part[64 + lane] + part[128 + lane] + part[192 + lane];
        atomicAdd(&pos_agg[d * 64 + lane], t);
    }
}

// ---------------- position update: pos_out = relu([pos_in, agg/cnt] @ W + b) ----------------
__global__ __launch_bounds__(256) void pos_update(const float* __restrict__ pos_in,
                                                  const float* __restrict__ agg,   // raw sums
                                                  const int* __restrict__ cnt,
                                                  const float* __restrict__ W,
                                                  const float* __restrict__ bias,
                                                  float* __restrict__ pos_out)
{
    int idx = blockIdx.x * 256 + threadIdx.x;
    if (idx >= NPOS * EMB) return;
    int r = idx >> 6, j = idx & 63;
    int c = cnt[r];
    float invc = 1.f / (float)(c < 1 ? 1 : c);
    float am = bias[j], aa = 0.f;
    const float* pr = pos_in + r * 64;
    const float* ar = agg + r * 64;
#pragma unroll 8
    for (int k = 0; k < 64; ++k) am += pr[k] * W[k * 64 + j];
#pragma unroll 8
    for (int k = 0; k < 64; ++k) aa += ar[k] * W[(64 + k) * 64 + j];
    pos_out[idx] = fmaxf(am + aa * invc, 0.f);
}

// ---------------- small fp32 linear (p2t messages, 320 rows) ----------------
template<int K, int M, bool RELU>
__global__ __launch_bounds__(256) void linear_rows(const float* __restrict__ A,
                                                   const float* __restrict__ W,
                                                   const float* __restrict__ bias,
                                                   float* __restrict__ out, int N)
{
    int r = blockIdx.x * 256 + threadIdx.x;
    if (r >= N) return;
    const float4* a4 = (const float4*)(A + (size_t)r * K);
    float* o = out + (size_t)r * M;
#pragma unroll 1
    for (int j0 = 0; j0 < M; j0 += 32) {
        float acc[32];
#pragma unroll
        for (int j = 0; j < 32; ++j) acc[j] = bias[j0 + j];
#pragma unroll 2
        for (int k4 = 0; k4 < K / 4; ++k4) {
            float4 av = a4[k4];
            const float* w0 = W + (size_t)(4 * k4) * M + j0;
#pragma unroll
            for (int j = 0; j < 32; ++j) acc[j] += av.x * w0[j];
            const float* w1 = w0 + M;
#pragma unroll
            for (int j = 0; j < 32; ++j) acc[j] += av.y * w1[j];
            const float* w2 = w1 + M;
#pragma unroll
            for (int j = 0; j < 32; ++j) acc[j] += av.z * w2[j];
            const float* w3 = w2 + M;
#pragma unroll
            for (int j = 0; j < 32; ++j) acc[j] += av.w * w3[j];
        }
#pragma unroll
        for (int j = 0; j < 32; ++j) {
            float v = acc[j];
            if (RELU) v = fmaxf(v, 0.f);
            o[j0 + j] = v;
        }
    }
}

// ---------------- p2t team rounds + game head (single block) ----------------
__global__ __launch_bounds__(256) void p2t_head(
    const float* __restrict__ Mt,
    const int* __restrict__ p2t_edges,
    const float* __restrict__ upd_w, const float* __restrict__ upd_b,
    const int* __restrict__ team_indices,
    const float* __restrict__ team_table,
    const int* __restrict__ home_p, const int* __restrict__ away_p,
    const float* __restrict__ gp_w1, const float* __restrict__ gp_b1,
    const float* __restrict__ gp_w2, const float* __restrict__ gp_b2,
    const float* __restrict__ gp_w3, const float* __restrict__ gp_b3,
    float* __restrict__ out)
{
    __shared__ int   tcnt[NT];
    __shared__ int   tlist[NT * T2_CAP];
    __shared__ float aggbar[NT * 64];
    __shared__ float teamA[NT * 64];
    __shared__ float teamB[NT * 64];
    __shared__ float z1[128];
    __shared__ float z2[64];
    int tid = threadIdx.x;

    if (tid < NT) tcnt[tid] = 0;
    __syncthreads();
    for (int e = tid; e < EP2T; e += 256) {
        int s = p2t_edges[e], d = p2t_edges[EP2T + e];
        int p = atomicAdd(&tcnt[d], 1);
        if (p < T2_CAP) tlist[d * T2_CAP + p] = s;
    }
    __syncthreads();
    for (int i = tid; i < NT * 64; i += 256) {
        int d = i >> 6, c = i & 63;
        int cn = tcnt[d];
        int cl = cn > T2_CAP ? T2_CAP : cn;
        float acc = 0.f;
        for (int j = 0; j < cl; ++j) acc += Mt[tlist[d * T2_CAP + j] * 64 + c];
        float dv = cn < 1 ? 1.f : (float)cn;
        aggbar[i] = acc / dv;
        teamA[i] = team_table[team_indices[d] * 64 + c];
    }
    __syncthreads();

    float* tin = teamA; float* tout = teamB;
    for (int round = 0; round < 3; ++round) {
        for (int i = tid; i < NT * 64; i += 256) {
            int r = i >> 6, j = i & 63;
            float acc = upd_b[j];
            for (int k = 0; k < 64; ++k) acc += tin[r * 64 + k] * upd_w[k * 64 + j];
            for (int k = 0; k < 64; ++k) acc += aggbar[r * 64 + k] * upd_w[(64 + k) * 64 + j];
            tout[i] = fmaxf(acc, 0.f);
        }
        __syncthreads();
        float* tmp = tin; tin = tout; tout = tmp;
    }

    int home = home_p[0], away = away_p[0];
    if (tid < 128) {
        float acc = gp_b1[tid];
        for (int k = 0; k < 128; ++k) {
            float g = (k < 64) ? tin[home * 64 + k] : tin[away * 64 + (k - 64)];
            acc += g * gp_w1[k * 128 + tid];
        }
        z1[tid] = fmaxf(acc, 0.f);
    }
    __syncthreads();
    if (tid < 64) {
        float acc = gp_b2[tid];
        for (int k = 0; k < 128; ++k) acc += z1[k] * gp_w2[k * 64 + tid];
        z2[tid] = fmaxf(acc, 0.f);
    }
    __syncthreads();
    if (tid == 0) {
        float acc = gp_b3[0];
        for (int k = 0; k < 64; ++k) acc += z2[k] * gp_w3[k];
        out[0] = 1.f / (1.f + __expf(-acc));
    }
}

// ---------------- host launcher ----------------
extern "C" void kernel_launch(void* const* d_in, const int* in_sizes, int n_in,
                              void* d_out, int out_size, void* d_ws, size_t ws_size,
                              hipStream_t stream)
{
    const float* X        = (const float*)d_in[0];
    const int*   pos_idx  = (const int*)d_in[1];
    const int*   team_idx = (const int*)d_in[2];
    const int*   p2p      = (const int*)d_in[3];
    const int*   p2t      = (const int*)d_in[4];
    const int*   chem     = (const int*)d_in[5];
    const int*   home_p   = (const int*)d_in[6];
    const int*   away_p   = (const int*)d_in[7];
    const float* enc_w1   = (const float*)d_in[8];
    const float* enc_b1   = (const float*)d_in[9];
    const float* enc_w2   = (const float*)d_in[10];
    const float* enc_b2   = (const float*)d_in[11];
    const float* pos_tab  = (const float*)d_in[12];
    const float* team_tab = (const float*)d_in[13];
    const float* q_w = (const float*)d_in[14]; const float* q_b = (const float*)d_in[15];
    const float* k_w = (const float*)d_in[16]; const float* k_b = (const float*)d_in[17];
    const float* v_w = (const float*)d_in[18]; const float* v_b = (const float*)d_in[19];
    const float* p2p_msg_w = (const float*)d_in[20]; const float* p2p_msg_b = (const float*)d_in[21];
    const float* p2p_upd_w = (const float*)d_in[22]; const float* p2p_upd_b = (const float*)d_in[23];
    const float* p2t_msg_w = (const float*)d_in[24]; const float* p2t_msg_b = (const float*)d_in[25];
    const float* p2t_upd_w = (const float*)d_in[26]; const float* p2t_upd_b = (const float*)d_in[27];
    const float* gp_w1 = (const float*)d_in[28]; const float* gp_b1 = (const float*)d_in[29];
    const float* gp_w2 = (const float*)d_in[30]; const float* gp_b2 = (const float*)d_in[31];
    const float* gp_w3 = (const float*)d_in[32]; const float* gp_b3 = (const float*)d_in[33];
    float* out = (float*)d_out;

    // ---- workspace layout (bytes), peak ~183 MB ----
    char* ws = (char*)d_ws;
    uint2*    swlist    = (uint2*)(ws + 0);            // NP*CHEM_CAP*8 = 51.2MB
    u16*      emb_b     = (u16*)  (ws + 51200000);     // NP*64 bf16 = 25.6MB
    u16*      Qb        = (u16*)  (ws + 76800000);
    u16*      Kb        = (u16*)  (ws + 102400000);
    u16*      Vb        = (u16*)  (ws + 128000000);
    u16*      Mpb       = (u16*)  (ws + 153600000);
    int*      p2p_list  = (int*)  (ws + 179200000);    // 2.62MB
    int*      chem_cnt  = (int*)  (ws + 181821440);    // 800KB
    int*      p2p_cnt   = (int*)  (ws + 182621440);
    float*    pos_agg   = (float*)(ws + 182622720);
    float*    posA      = (float*)(ws + 182704640);
    float*    posB      = (float*)(ws + 182786560);
    float*    Mt        = (float*)(ws + 182868480);
    float*    Zp        = (float*)(ws + 182950400);
    u16*      Wpack     = (u16*)  (ws + 182950416);    // 80KB transposed bf16 weights
    u16* W1t  = Wpack;
    u16* W2t  = Wpack + 16384;
    u16* Qt   = Wpack + 24576;
    u16* Kt   = Wpack + 28672;
    u16* Vt   = Wpack + 32768;
    u16* Msgt = Wpack + 36864;

    const int NB_NP = (NP + 255) / 256;

    hipLaunchKernelGGL(init_kernel, dim3(NB_NP), dim3(256), 0, stream,
                       chem_cnt, p2p_cnt, Zp, pos_idx, pos_tab, posA, pos_agg,
                       enc_w1, enc_w2, q_w, k_w, v_w, p2p_msg_w, Wpack);
    // fused encoder + QKV (MFMA)
    hipLaunchKernelGGL(mfma_enc, dim3(NP / 64), dim3(256), 0, stream,
                       X, W1t, W2t, Qt, Kt, Vt,
                       enc_b1, enc_b2, q_b, k_b, v_b,
                       emb_b, Qb, Kb, Vb);
    // fused chem attention: scores + exp + Z + scatter
    hipLaunchKernelGGL(chem_attn, dim3(SC_GRID), dim3(256), 0, stream,
                       Qb, Kb, chem, chem_cnt, swlist, Zp);
    // fused chem aggregation + p2p message GEMM
    hipLaunchKernelGGL(chem_agg_msg, dim3(NP / 64), dim3(256), 0, stream,
                       emb_b, Vb, chem_cnt, swlist, Zp, Msgt, p2p_msg_b, Mpb);
    // p2p phase
    hipLaunchKernelGGL(p2p_bucket, dim3(PB_BLOCKS), dim3(256), 0, stream, p2p, p2p_cnt, p2p_list);
    hipLaunchKernelGGL(p2p_agg, dim3(NPOS * AGG_SPLIT), dim3(256), 0, stream,
                       Mpb, p2p_cnt, p2p_list, pos_agg);
    hipLaunchKernelGGL(pos_update, dim3((NPOS * EMB + 255) / 256), dim3(256), 0, stream,
                       posA, pos_agg, p2p_cnt, p2p_upd_w, p2p_upd_b, posB);
    hipLaunchKernelGGL(pos_update, dim3((NPOS * EMB + 255) / 256), dim3(256), 0, stream,
                       posB, pos_agg, p2p_cnt, p2p_upd_w, p2p_upd_b, posA);
    hipLaunchKernelGGL(pos_update, dim3((NPOS * EMB + 255) / 256), dim3(256), 0, stream,
                       posA, pos_agg, p2p_cnt, p2p_upd_w, p2p_upd_b, posB);
    // p2t phase + head
    hipLaunchKernelGGL((linear_rows<64,64,true>), dim3((NPOS + 255) / 256), dim3(256), 0, stream,
                       posB, p2t_msg_w, p2t_msg_b, Mt, NPOS);
    hipLaunchKernelGGL(p2t_head, dim3(1), dim3(256), 0, stream,
                       Mt, p2t, p2t_upd_w, p2t_upd_b, team_idx, team_tab, home_p, away_p,
                       gp_w1, gp_b1, gp_w2, gp_b2, gp_w3, gp_b3, out);
}